// Round 3
// baseline (3210.911 us; speedup 1.0000x reference)
//
#include <hip/hip_runtime.h>
#include <cstdint>
#include <cstddef>

// Problem geometry (fixed by reference setup_inputs):
//   h: (64, 512, 32, 32) fp32;  chw = 512*32*32 = 2^19
//   k0 = int(0.1 * chw) = 52428; rank (ascending, 0-indexed) = chw-1-k0 = 471859
//   out = h * (|h| >= cutoff ? 1.0 : (1 - tau))
#define CHW 524288
#define F4_PER_SAMPLE (CHW / 4)            // 131072
#define BLOCKS_PER_SAMPLE 64
#define F4_PER_BLOCK (F4_PER_SAMPLE / BLOCKS_PER_SAMPLE)  // 2048
#define NTHREADS 256
#define F4_PER_THREAD (F4_PER_BLOCK / NTHREADS)           // 8
#define NB12 4096                           // 12-bit histogram
#define NB7  128                            // final 7-bit histogram
#define CAP_PER_SAMPLE 49152                // candidate cap (avg ~33.4k, sigma ~180)
// Candidate window [1.5, 1.8125), aligned to 12-bit key bins.
// bits(1.5f)=0x3FC00000 -> bin 2040; bin 2045 -> 1.8125f.
#define WIN_LO_BIN 2040u
#define WIN_HI_BIN 2045u
#define WIN_LO_KEY (WIN_LO_BIN << 19)
#define WIN_HI_KEY (WIN_HI_BIN << 19)

__device__ __forceinline__ unsigned int akey(float x) {
    return __float_as_uint(x) & 0x7FFFFFFFu;   // monotonic key for |x|
}

// ---------------- zero workspace words ----------------
__global__ __launch_bounds__(NTHREADS) void zero_ws(unsigned int* __restrict__ p, int words) {
    int i = blockIdx.x * NTHREADS + threadIdx.x;
    if (i < words) p[i] = 0u;
}

// ============================================================================
// FAST PATH: fused 12-bit histogram + window candidate compaction
// ============================================================================
__global__ __launch_bounds__(NTHREADS) void hist_compact(const float4* __restrict__ h,
                                                         unsigned int* __restrict__ hist,
                                                         unsigned int* __restrict__ cand,
                                                         unsigned int* __restrict__ ccount) {
    __shared__ unsigned int lh[NB12];
    const int t = threadIdx.x;
    for (int i = t; i < NB12; i += NTHREADS) lh[i] = 0;
    __syncthreads();

    const int n = blockIdx.x >> 6;
    const int chunk = blockIdx.x & 63;
    const float4* p = h + (size_t)n * F4_PER_SAMPLE + (size_t)chunk * F4_PER_BLOCK;
    unsigned int* mycand = cand + (size_t)n * CAP_PER_SAMPLE;
    unsigned int* myc = ccount + n;
    const int lane = t & 63;

#pragma unroll
    for (int k = 0; k < F4_PER_THREAD; ++k) {
        float4 v = p[k * NTHREADS + t];
        unsigned int kk[4] = { akey(v.x), akey(v.y), akey(v.z), akey(v.w) };
#pragma unroll
        for (int c = 0; c < 4; ++c) {
            unsigned int key = kk[c];
            atomicAdd(&lh[key >> 19], 1u);
            bool pred = (key >= WIN_LO_KEY) & (key < WIN_HI_KEY);
            unsigned long long m = __ballot(pred);
            if (m) {
                int cnt = __popcll(m);
                int leader = __ffsll((long long)m) - 1;
                unsigned int base = 0;
                if (lane == leader) base = atomicAdd(myc, (unsigned int)cnt);
                base = __shfl(base, leader);
                if (pred) {
                    unsigned int pos = base + (unsigned int)__popcll(m & ((1ull << lane) - 1ull));
                    if (pos < CAP_PER_SAMPLE) mycand[pos] = key;
                }
            }
        }
    }
    __syncthreads();

    unsigned int* gh = hist + (size_t)n * NB12;
    for (int i = t; i < NB12; i += NTHREADS) {
        unsigned int v = lh[i];
        if (v) atomicAdd(&gh[i], v);
    }
}

// ---------------- per-sample 3-level select over hist + candidate list ----------------
__global__ __launch_bounds__(NTHREADS) void select_cand(const unsigned int* __restrict__ hist,
                                                        const unsigned int* __restrict__ cand,
                                                        const unsigned int* __restrict__ ccount,
                                                        const float* __restrict__ h,
                                                        unsigned int* __restrict__ cutk,
                                                        unsigned int rank) {
    __shared__ unsigned int lh[NB12];
    __shared__ unsigned int part[NTHREADS];
    __shared__ unsigned int sb1, sr1, sb2, sr2;
    const int n = blockIdx.x;
    const int t = threadIdx.x;
    const unsigned int* gh = hist + (size_t)n * NB12;

    // ---- level 1: coarse 12-bit bin from global histogram ----
    unsigned int s = 0;
    const int b0 = t * (NB12 / NTHREADS);     // 16 bins per thread
    for (int i = 0; i < NB12 / NTHREADS; ++i) s += gh[b0 + i];
    part[t] = s;
    __syncthreads();
    for (int off = 1; off < NTHREADS; off <<= 1) {
        unsigned int v = (t >= off) ? part[t - off] : 0u;
        __syncthreads();
        part[t] += v;
        __syncthreads();
    }
    {
        unsigned int excl = part[t] - s;
        if (s > 0 && rank >= excl && rank < excl + s) {
            unsigned int acc = excl;
            for (int i = 0; i < NB12 / NTHREADS; ++i) {
                unsigned int c = gh[b0 + i];
                if (rank < acc + c) { sb1 = (unsigned int)(b0 + i); sr1 = rank - acc; break; }
                acc += c;
            }
        }
    }
    __syncthreads();
    const unsigned int b1 = sb1, r1 = sr1;

    // candidate list valid iff cutoff bin inside window and no counter overflow
    const unsigned int cn = ccount[n];
    const bool use_cand = (cn <= CAP_PER_SAMPLE) && (b1 >= WIN_LO_BIN) && (b1 < WIN_HI_BIN);
    const unsigned int len = use_cand ? cn : (unsigned int)CHW;
    const unsigned int* clist = cand + (size_t)n * CAP_PER_SAMPLE;
    const float* hp = h + (size_t)n * CHW;

    // ---- level 2: bits 18:7 among keys with top12 == b1 ----
    for (int i = t; i < NB12; i += NTHREADS) lh[i] = 0;
    __syncthreads();
    for (unsigned int i = t; i < len; i += NTHREADS) {
        unsigned int key = use_cand ? clist[i] : akey(hp[i]);
        if ((key >> 19) == b1) atomicAdd(&lh[(key >> 7) & 0xFFFu], 1u);
    }
    __syncthreads();
    unsigned int s2 = 0;
    for (int i = 0; i < NB12 / NTHREADS; ++i) s2 += lh[b0 + i];
    part[t] = s2;
    __syncthreads();
    for (int off = 1; off < NTHREADS; off <<= 1) {
        unsigned int v = (t >= off) ? part[t - off] : 0u;
        __syncthreads();
        part[t] += v;
        __syncthreads();
    }
    {
        unsigned int excl = part[t] - s2;
        if (s2 > 0 && r1 >= excl && r1 < excl + s2) {
            unsigned int acc = excl;
            for (int i = 0; i < NB12 / NTHREADS; ++i) {
                unsigned int c = lh[b0 + i];
                if (r1 < acc + c) { sb2 = (unsigned int)(b0 + i); sr2 = r1 - acc; break; }
                acc += c;
            }
        }
    }
    __syncthreads();
    const unsigned int b2 = sb2, r2 = sr2;
    const unsigned int p24 = (b1 << 12) | b2;

    // ---- level 3: low 7 bits among keys with top24 == p24 ----
    if (t < NB7) lh[t] = 0;
    __syncthreads();
    for (unsigned int i = t; i < len; i += NTHREADS) {
        unsigned int key = use_cand ? clist[i] : akey(hp[i]);
        if ((key >> 7) == p24) atomicAdd(&lh[key & 0x7Fu], 1u);
    }
    __syncthreads();
    if (t == 0) {
        unsigned int acc = 0;
        for (int b = 0; b < NB7; ++b) {
            unsigned int c = lh[b];
            if (r2 < acc + c) { cutk[n] = (p24 << 7) | (unsigned int)b; break; }
            acc += c;
        }
    }
}

// ============================================================================
// FALLBACK PATH (small d_ws): original 3-pass radix select
// ============================================================================
__global__ __launch_bounds__(NTHREADS) void hist_pass1(const float4* __restrict__ h,
                                                       unsigned int* __restrict__ hist) {
    __shared__ unsigned int lh[NB12];
    const int t = threadIdx.x;
    for (int i = t; i < NB12; i += NTHREADS) lh[i] = 0;
    __syncthreads();
    const int n = blockIdx.x >> 6;
    const int chunk = blockIdx.x & 63;
    const float4* p = h + (size_t)n * F4_PER_SAMPLE + (size_t)chunk * F4_PER_BLOCK;
#pragma unroll
    for (int k = 0; k < F4_PER_THREAD; ++k) {
        float4 v = p[k * NTHREADS + t];
        atomicAdd(&lh[akey(v.x) >> 19], 1u);
        atomicAdd(&lh[akey(v.y) >> 19], 1u);
        atomicAdd(&lh[akey(v.z) >> 19], 1u);
        atomicAdd(&lh[akey(v.w) >> 19], 1u);
    }
    __syncthreads();
    unsigned int* gh = hist + (size_t)n * NB12;
    for (int i = t; i < NB12; i += NTHREADS) {
        unsigned int v = lh[i];
        if (v) atomicAdd(&gh[i], v);
    }
}

__global__ __launch_bounds__(NTHREADS) void hist_pass2(const float4* __restrict__ h,
                                                       const unsigned int* __restrict__ state_bits,
                                                       unsigned int* __restrict__ hist) {
    __shared__ unsigned int lh[NB12];
    const int t = threadIdx.x;
    for (int i = t; i < NB12; i += NTHREADS) lh[i] = 0;
    __syncthreads();
    const int n = blockIdx.x >> 6;
    const int chunk = blockIdx.x & 63;
    const unsigned int b1 = state_bits[n];
    const float4* p = h + (size_t)n * F4_PER_SAMPLE + (size_t)chunk * F4_PER_BLOCK;
#pragma unroll
    for (int k = 0; k < F4_PER_THREAD; ++k) {
        float4 v = p[k * NTHREADS + t];
        unsigned int ka = akey(v.x), kb = akey(v.y), kc = akey(v.z), kd = akey(v.w);
        if ((ka >> 19) == b1) atomicAdd(&lh[(ka >> 7) & 0xFFFu], 1u);
        if ((kb >> 19) == b1) atomicAdd(&lh[(kb >> 7) & 0xFFFu], 1u);
        if ((kc >> 19) == b1) atomicAdd(&lh[(kc >> 7) & 0xFFFu], 1u);
        if ((kd >> 19) == b1) atomicAdd(&lh[(kd >> 7) & 0xFFFu], 1u);
    }
    __syncthreads();
    unsigned int* gh = hist + (size_t)n * NB12;
    for (int i = t; i < NB12; i += NTHREADS) {
        unsigned int v = lh[i];
        if (v) atomicAdd(&gh[i], v);
    }
}

__global__ __launch_bounds__(NTHREADS) void hist_pass3(const float4* __restrict__ h,
                                                       const unsigned int* __restrict__ state_bits,
                                                       unsigned int* __restrict__ hist) {
    __shared__ unsigned int lh[NB7];
    const int t = threadIdx.x;
    for (int i = t; i < NB7; i += NTHREADS) lh[i] = 0;
    __syncthreads();
    const int n = blockIdx.x >> 6;
    const int chunk = blockIdx.x & 63;
    const unsigned int p24 = state_bits[n];
    const float4* p = h + (size_t)n * F4_PER_SAMPLE + (size_t)chunk * F4_PER_BLOCK;
#pragma unroll
    for (int k = 0; k < F4_PER_THREAD; ++k) {
        float4 v = p[k * NTHREADS + t];
        unsigned int ka = akey(v.x), kb = akey(v.y), kc = akey(v.z), kd = akey(v.w);
        if ((ka >> 7) == p24) atomicAdd(&lh[ka & 0x7Fu], 1u);
        if ((kb >> 7) == p24) atomicAdd(&lh[kb & 0x7Fu], 1u);
        if ((kc >> 7) == p24) atomicAdd(&lh[kc & 0x7Fu], 1u);
        if ((kd >> 7) == p24) atomicAdd(&lh[kd & 0x7Fu], 1u);
    }
    __syncthreads();
    unsigned int* gh = hist + (size_t)n * NB7;
    for (int i = t; i < NB7; i += NTHREADS) {
        unsigned int v = lh[i];
        if (v) atomicAdd(&gh[i], v);
    }
}

__global__ __launch_bounds__(NTHREADS) void select_pass(const unsigned int* __restrict__ hist,
                                                        int nbins, int pass,
                                                        unsigned int* __restrict__ state_bits,
                                                        unsigned int* __restrict__ state_rank,
                                                        unsigned int* __restrict__ cutoff,
                                                        unsigned int init_rank) {
    const int n = blockIdx.x;
    const int t = threadIdx.x;
    const int bpt = (nbins + NTHREADS - 1) / NTHREADS;
    const unsigned int* gh = hist + (size_t)n * nbins;
    unsigned int s = 0;
    const int b0 = t * bpt;
    for (int i = 0; i < bpt; ++i) {
        int b = b0 + i;
        if (b < nbins) s += gh[b];
    }
    __shared__ unsigned int part[NTHREADS];
    part[t] = s;
    __syncthreads();
    for (int off = 1; off < NTHREADS; off <<= 1) {
        unsigned int v = (t >= off) ? part[t - off] : 0u;
        __syncthreads();
        part[t] += v;
        __syncthreads();
    }
    const unsigned int excl = part[t] - s;
    const unsigned int r = (pass == 0) ? init_rank : state_rank[n];
    if (s > 0 && r >= excl && r < excl + s) {
        unsigned int acc = excl;
        for (int i = 0; i < bpt; ++i) {
            int b = b0 + i;
            unsigned int c = gh[b];
            if (r < acc + c) {
                if (pass == 0) { state_bits[n] = (unsigned int)b; state_rank[n] = r - acc; }
                else if (pass == 1) { state_bits[n] = (state_bits[n] << 12) | (unsigned int)b; state_rank[n] = r - acc; }
                else { cutoff[n] = (state_bits[n] << 7) | (unsigned int)b; }
                break;
            }
            acc += c;
        }
    }
}

// ---------------- Apply: out = h * (key >= cutoff ? 1.0 : (1 - tau)) ----------------
__global__ __launch_bounds__(NTHREADS) void apply_kernel(const float4* __restrict__ h,
                                                         const float* __restrict__ tau,
                                                         const unsigned int* __restrict__ cutoff,
                                                         float4* __restrict__ out) {
    const int n = blockIdx.x >> 6;
    const int chunk = blockIdx.x & 63;
    const unsigned int c = cutoff[n];
    const float t = tau[0];
    const float lo = 1.0f - t;
    const size_t base = (size_t)n * F4_PER_SAMPLE + (size_t)chunk * F4_PER_BLOCK;
    const int tid = threadIdx.x;
#pragma unroll
    for (int k = 0; k < F4_PER_THREAD; ++k) {
        float4 v = h[base + k * NTHREADS + tid];
        float4 o;
        o.x = v.x * ((akey(v.x) >= c) ? 1.0f : lo);
        o.y = v.y * ((akey(v.y) >= c) ? 1.0f : lo);
        o.z = v.z * ((akey(v.z) >= c) ? 1.0f : lo);
        o.w = v.w * ((akey(v.w) >= c) ? 1.0f : lo);
        out[base + k * NTHREADS + tid] = o;
    }
}

extern "C" void kernel_launch(void* const* d_in, const int* in_sizes, int n_in,
                              void* d_out, int out_size, void* d_ws, size_t ws_size,
                              hipStream_t stream) {
    const float* h = (const float*)d_in[0];
    const float* tau = (const float*)d_in[1];
    float* out = (float*)d_out;

    const int total = in_sizes[0];
    const int N = total / CHW;              // 64

    const int k0 = (int)(0.1 * (double)CHW);                      // 52428
    const unsigned int init_rank = (unsigned int)(CHW - 1 - k0);  // 471859

    dim3 grid((unsigned)(N * BLOCKS_PER_SAMPLE)), blk(NTHREADS);

    // ---- fast path layout: hist1 | ccount | cutk | cand ----
    const size_t fast_words = (size_t)N * NB12 + (size_t)N + (size_t)N + (size_t)N * CAP_PER_SAMPLE;
    if (ws_size >= fast_words * 4) {
        unsigned int* hist1 = (unsigned int*)d_ws;
        unsigned int* ccnt  = hist1 + (size_t)N * NB12;
        unsigned int* cutk  = ccnt + N;
        unsigned int* cand  = cutk + N;

        const int zwords = N * NB12 + N;                 // hist1 + ccnt
        zero_ws<<<(zwords + NTHREADS - 1) / NTHREADS, blk, 0, stream>>>(hist1, zwords);
        hist_compact<<<grid, blk, 0, stream>>>((const float4*)h, hist1, cand, ccnt);
        select_cand<<<N, blk, 0, stream>>>(hist1, cand, ccnt, h, cutk, init_rank);
        apply_kernel<<<grid, blk, 0, stream>>>((const float4*)h, tau, cutk, (float4*)out);
        return;
    }

    // ---- fallback: original 3-pass path (needs ~2.2 MB ws) ----
    unsigned int* hist1 = (unsigned int*)d_ws;
    unsigned int* hist2 = hist1 + (size_t)N * NB12;
    unsigned int* hist3 = hist2 + (size_t)N * NB12;
    unsigned int* sbits = hist3 + (size_t)N * NB7;
    unsigned int* srank = sbits + N;
    unsigned int* cutk  = srank + N;
    const int zwords = 2 * N * NB12 + N * NB7 + 3 * N;

    zero_ws<<<(zwords + NTHREADS - 1) / NTHREADS, blk, 0, stream>>>(hist1, zwords);
    hist_pass1<<<grid, blk, 0, stream>>>((const float4*)h, hist1);
    select_pass<<<N, blk, 0, stream>>>(hist1, NB12, 0, sbits, srank, cutk, init_rank);
    hist_pass2<<<grid, blk, 0, stream>>>((const float4*)h, sbits, hist2);
    select_pass<<<N, blk, 0, stream>>>(hist2, NB12, 1, sbits, srank, cutk, 0u);
    hist_pass3<<<grid, blk, 0, stream>>>((const float4*)h, sbits, hist3);
    select_pass<<<N, blk, 0, stream>>>(hist3, NB7, 2, sbits, srank, cutk, 0u);
    apply_kernel<<<grid, blk, 0, stream>>>((const float4*)h, tau, cutk, (float4*)out);
}

// Round 4
// 184.158 us; speedup vs baseline: 17.4356x; 17.4356x over previous
//
#include <hip/hip_runtime.h>
#include <cstdint>
#include <cstddef>

// Problem geometry (fixed by reference setup_inputs):
//   h: (64, 512, 32, 32) fp32;  chw = 512*32*32 = 2^19
//   k0 = int(0.1 * chw) = 52428; rank (ascending, 0-indexed) = chw-1-k0 = 471859
//   out = h * (|h| >= cutoff ? 1.0 : (1 - tau))
#define CHW 524288
#define F4_PER_SAMPLE (CHW / 4)            // 131072
#define BLOCKS_PER_SAMPLE 64
#define F4_PER_BLOCK (F4_PER_SAMPLE / BLOCKS_PER_SAMPLE)  // 2048
#define NTHREADS 256
#define F4_PER_THREAD (F4_PER_BLOCK / NTHREADS)           // 8
#define NB12 4096                           // 12-bit histogram
#define NB7  128                            // final 7-bit histogram
#define CAP_PER_SAMPLE 49152                // global candidate cap (avg ~33.4k)
#define LCAP 1024                           // per-block LDS candidate cap (avg ~524, sd ~22)
// Candidate window [1.5, 1.8125), aligned to 12-bit key bins.
// bits(1.5f)=0x3FC00000 -> bin 2040; bin 2045 -> 1.8125f.
#define WIN_LO_BIN 2040u
#define WIN_HI_BIN 2045u
#define WIN_LO_KEY (WIN_LO_BIN << 19)
#define WIN_HI_KEY (WIN_HI_BIN << 19)

__device__ __forceinline__ unsigned int akey(float x) {
    return __float_as_uint(x) & 0x7FFFFFFFu;   // monotonic key for |x|
}

// ---------------- zero workspace words ----------------
__global__ __launch_bounds__(NTHREADS) void zero_ws(unsigned int* __restrict__ p, int words) {
    int i = blockIdx.x * NTHREADS + threadIdx.x;
    if (i < words) p[i] = 0u;
}

// ============================================================================
// FAST PATH: fused 12-bit histogram + window candidate compaction.
// Candidates staged in LDS; ONE global atomic per block (R3 post-mortem:
// per-ballot global atomics to 4 cachelines serialized the whole kernel).
// ============================================================================
__global__ __launch_bounds__(NTHREADS) void hist_compact(const float4* __restrict__ h,
                                                         unsigned int* __restrict__ hist,
                                                         unsigned int* __restrict__ cand,
                                                         unsigned int* __restrict__ ccount,
                                                         unsigned int* __restrict__ ovfl) {
    __shared__ unsigned int lh[NB12];
    __shared__ unsigned int lbuf[LCAP];
    __shared__ unsigned int lcnt;
    __shared__ unsigned int gbase;
    const int t = threadIdx.x;
    for (int i = t; i < NB12; i += NTHREADS) lh[i] = 0;
    if (t == 0) lcnt = 0u;
    __syncthreads();

    const int n = blockIdx.x >> 6;
    const int chunk = blockIdx.x & 63;
    const float4* p = h + (size_t)n * F4_PER_SAMPLE + (size_t)chunk * F4_PER_BLOCK;
    const int lane = t & 63;

#pragma unroll
    for (int k = 0; k < F4_PER_THREAD; ++k) {
        float4 v = p[k * NTHREADS + t];
        unsigned int kk[4] = { akey(v.x), akey(v.y), akey(v.z), akey(v.w) };
#pragma unroll
        for (int c = 0; c < 4; ++c) {
            unsigned int key = kk[c];
            atomicAdd(&lh[key >> 19], 1u);
            bool pred = (key >= WIN_LO_KEY) & (key < WIN_HI_KEY);
            unsigned long long m = __ballot(pred);
            if (m) {
                int leader = __ffsll((long long)m) - 1;
                unsigned int base = 0;
                if (lane == leader) base = atomicAdd(&lcnt, (unsigned int)__popcll(m));
                base = __shfl(base, leader);
                if (pred) {
                    unsigned int pos = base + (unsigned int)__popcll(m & ((1ull << lane) - 1ull));
                    if (pos < LCAP) lbuf[pos] = key;
                }
            }
        }
    }
    __syncthreads();

    // flush histogram
    unsigned int* gh = hist + (size_t)n * NB12;
    for (int i = t; i < NB12; i += NTHREADS) {
        unsigned int v = lh[i];
        if (v) atomicAdd(&gh[i], v);
    }

    // flush candidates: one global atomic per block, coalesced copy
    const unsigned int total = lcnt;
    const unsigned int wcnt = (total < (unsigned int)LCAP) ? total : (unsigned int)LCAP;
    if (t == 0) {
        gbase = atomicAdd(&ccount[n], wcnt);
        if (total > (unsigned int)LCAP) atomicOr(&ovfl[n], 1u);
    }
    __syncthreads();
    const unsigned int base = gbase;
    unsigned int* mycand = cand + (size_t)n * CAP_PER_SAMPLE;
    for (unsigned int i = t; i < wcnt; i += NTHREADS) {
        unsigned int pos = base + i;
        if (pos < CAP_PER_SAMPLE) mycand[pos] = lbuf[i];
    }
}

// ---------------- per-sample 3-level select over hist + candidate list ----------------
__global__ __launch_bounds__(NTHREADS) void select_cand(const unsigned int* __restrict__ hist,
                                                        const unsigned int* __restrict__ cand,
                                                        const unsigned int* __restrict__ ccount,
                                                        const unsigned int* __restrict__ ovfl,
                                                        const float* __restrict__ h,
                                                        unsigned int* __restrict__ cutk,
                                                        unsigned int rank) {
    __shared__ unsigned int lh[NB12];
    __shared__ unsigned int part[NTHREADS];
    __shared__ unsigned int sb1, sr1, sb2, sr2;
    const int n = blockIdx.x;
    const int t = threadIdx.x;
    const unsigned int* gh = hist + (size_t)n * NB12;

    // ---- level 1: coarse 12-bit bin from global histogram ----
    unsigned int s = 0;
    const int b0 = t * (NB12 / NTHREADS);     // 16 bins per thread
    for (int i = 0; i < NB12 / NTHREADS; ++i) s += gh[b0 + i];
    part[t] = s;
    __syncthreads();
    for (int off = 1; off < NTHREADS; off <<= 1) {
        unsigned int v = (t >= off) ? part[t - off] : 0u;
        __syncthreads();
        part[t] += v;
        __syncthreads();
    }
    {
        unsigned int excl = part[t] - s;
        if (s > 0 && rank >= excl && rank < excl + s) {
            unsigned int acc = excl;
            for (int i = 0; i < NB12 / NTHREADS; ++i) {
                unsigned int c = gh[b0 + i];
                if (rank < acc + c) { sb1 = (unsigned int)(b0 + i); sr1 = rank - acc; break; }
                acc += c;
            }
        }
    }
    __syncthreads();
    const unsigned int b1 = sb1, r1 = sr1;

    // candidate list valid iff no block overflowed, no global truncation,
    // and the cutoff bin lies inside the window
    const unsigned int cn = ccount[n];
    const bool use_cand = (ovfl[n] == 0u) && (cn <= (unsigned int)CAP_PER_SAMPLE) &&
                          (b1 >= WIN_LO_BIN) && (b1 < WIN_HI_BIN);
    const unsigned int len = use_cand ? cn : (unsigned int)CHW;
    const unsigned int* clist = cand + (size_t)n * CAP_PER_SAMPLE;
    const float* hp = h + (size_t)n * CHW;

    // ---- level 2: bits 18:7 among keys with top12 == b1 ----
    for (int i = t; i < NB12; i += NTHREADS) lh[i] = 0;
    __syncthreads();
    for (unsigned int i = t; i < len; i += NTHREADS) {
        unsigned int key = use_cand ? clist[i] : akey(hp[i]);
        if ((key >> 19) == b1) atomicAdd(&lh[(key >> 7) & 0xFFFu], 1u);
    }
    __syncthreads();
    unsigned int s2 = 0;
    for (int i = 0; i < NB12 / NTHREADS; ++i) s2 += lh[b0 + i];
    part[t] = s2;
    __syncthreads();
    for (int off = 1; off < NTHREADS; off <<= 1) {
        unsigned int v = (t >= off) ? part[t - off] : 0u;
        __syncthreads();
        part[t] += v;
        __syncthreads();
    }
    {
        unsigned int excl = part[t] - s2;
        if (s2 > 0 && r1 >= excl && r1 < excl + s2) {
            unsigned int acc = excl;
            for (int i = 0; i < NB12 / NTHREADS; ++i) {
                unsigned int c = lh[b0 + i];
                if (r1 < acc + c) { sb2 = (unsigned int)(b0 + i); sr2 = r1 - acc; break; }
                acc += c;
            }
        }
    }
    __syncthreads();
    const unsigned int b2 = sb2, r2 = sr2;
    const unsigned int p24 = (b1 << 12) | b2;

    // ---- level 3: low 7 bits among keys with top24 == p24 ----
    if (t < NB7) lh[t] = 0;
    __syncthreads();
    for (unsigned int i = t; i < len; i += NTHREADS) {
        unsigned int key = use_cand ? clist[i] : akey(hp[i]);
        if ((key >> 7) == p24) atomicAdd(&lh[key & 0x7Fu], 1u);
    }
    __syncthreads();
    if (t == 0) {
        unsigned int acc = 0;
        for (int b = 0; b < NB7; ++b) {
            unsigned int c = lh[b];
            if (r2 < acc + c) { cutk[n] = (p24 << 7) | (unsigned int)b; break; }
            acc += c;
        }
    }
}

// ============================================================================
// FALLBACK PATH (small d_ws): original 3-pass radix select
// ============================================================================
__global__ __launch_bounds__(NTHREADS) void hist_pass1(const float4* __restrict__ h,
                                                       unsigned int* __restrict__ hist) {
    __shared__ unsigned int lh[NB12];
    const int t = threadIdx.x;
    for (int i = t; i < NB12; i += NTHREADS) lh[i] = 0;
    __syncthreads();
    const int n = blockIdx.x >> 6;
    const int chunk = blockIdx.x & 63;
    const float4* p = h + (size_t)n * F4_PER_SAMPLE + (size_t)chunk * F4_PER_BLOCK;
#pragma unroll
    for (int k = 0; k < F4_PER_THREAD; ++k) {
        float4 v = p[k * NTHREADS + t];
        atomicAdd(&lh[akey(v.x) >> 19], 1u);
        atomicAdd(&lh[akey(v.y) >> 19], 1u);
        atomicAdd(&lh[akey(v.z) >> 19], 1u);
        atomicAdd(&lh[akey(v.w) >> 19], 1u);
    }
    __syncthreads();
    unsigned int* gh = hist + (size_t)n * NB12;
    for (int i = t; i < NB12; i += NTHREADS) {
        unsigned int v = lh[i];
        if (v) atomicAdd(&gh[i], v);
    }
}

__global__ __launch_bounds__(NTHREADS) void hist_pass2(const float4* __restrict__ h,
                                                       const unsigned int* __restrict__ state_bits,
                                                       unsigned int* __restrict__ hist) {
    __shared__ unsigned int lh[NB12];
    const int t = threadIdx.x;
    for (int i = t; i < NB12; i += NTHREADS) lh[i] = 0;
    __syncthreads();
    const int n = blockIdx.x >> 6;
    const int chunk = blockIdx.x & 63;
    const unsigned int b1 = state_bits[n];
    const float4* p = h + (size_t)n * F4_PER_SAMPLE + (size_t)chunk * F4_PER_BLOCK;
#pragma unroll
    for (int k = 0; k < F4_PER_THREAD; ++k) {
        float4 v = p[k * NTHREADS + t];
        unsigned int ka = akey(v.x), kb = akey(v.y), kc = akey(v.z), kd = akey(v.w);
        if ((ka >> 19) == b1) atomicAdd(&lh[(ka >> 7) & 0xFFFu], 1u);
        if ((kb >> 19) == b1) atomicAdd(&lh[(kb >> 7) & 0xFFFu], 1u);
        if ((kc >> 19) == b1) atomicAdd(&lh[(kc >> 7) & 0xFFFu], 1u);
        if ((kd >> 19) == b1) atomicAdd(&lh[(kd >> 7) & 0xFFFu], 1u);
    }
    __syncthreads();
    unsigned int* gh = hist + (size_t)n * NB12;
    for (int i = t; i < NB12; i += NTHREADS) {
        unsigned int v = lh[i];
        if (v) atomicAdd(&gh[i], v);
    }
}

__global__ __launch_bounds__(NTHREADS) void hist_pass3(const float4* __restrict__ h,
                                                       const unsigned int* __restrict__ state_bits,
                                                       unsigned int* __restrict__ hist) {
    __shared__ unsigned int lh[NB7];
    const int t = threadIdx.x;
    for (int i = t; i < NB7; i += NTHREADS) lh[i] = 0;
    __syncthreads();
    const int n = blockIdx.x >> 6;
    const int chunk = blockIdx.x & 63;
    const unsigned int p24 = state_bits[n];
    const float4* p = h + (size_t)n * F4_PER_SAMPLE + (size_t)chunk * F4_PER_BLOCK;
#pragma unroll
    for (int k = 0; k < F4_PER_THREAD; ++k) {
        float4 v = p[k * NTHREADS + t];
        unsigned int ka = akey(v.x), kb = akey(v.y), kc = akey(v.z), kd = akey(v.w);
        if ((ka >> 7) == p24) atomicAdd(&lh[ka & 0x7Fu], 1u);
        if ((kb >> 7) == p24) atomicAdd(&lh[kb & 0x7Fu], 1u);
        if ((kc >> 7) == p24) atomicAdd(&lh[kc & 0x7Fu], 1u);
        if ((kd >> 7) == p24) atomicAdd(&lh[kd & 0x7Fu], 1u);
    }
    __syncthreads();
    unsigned int* gh = hist + (size_t)n * NB7;
    for (int i = t; i < NB7; i += NTHREADS) {
        unsigned int v = lh[i];
        if (v) atomicAdd(&gh[i], v);
    }
}

__global__ __launch_bounds__(NTHREADS) void select_pass(const unsigned int* __restrict__ hist,
                                                        int nbins, int pass,
                                                        unsigned int* __restrict__ state_bits,
                                                        unsigned int* __restrict__ state_rank,
                                                        unsigned int* __restrict__ cutoff,
                                                        unsigned int init_rank) {
    const int n = blockIdx.x;
    const int t = threadIdx.x;
    const int bpt = (nbins + NTHREADS - 1) / NTHREADS;
    const unsigned int* gh = hist + (size_t)n * nbins;
    unsigned int s = 0;
    const int b0 = t * bpt;
    for (int i = 0; i < bpt; ++i) {
        int b = b0 + i;
        if (b < nbins) s += gh[b];
    }
    __shared__ unsigned int part[NTHREADS];
    part[t] = s;
    __syncthreads();
    for (int off = 1; off < NTHREADS; off <<= 1) {
        unsigned int v = (t >= off) ? part[t - off] : 0u;
        __syncthreads();
        part[t] += v;
        __syncthreads();
    }
    const unsigned int excl = part[t] - s;
    const unsigned int r = (pass == 0) ? init_rank : state_rank[n];
    if (s > 0 && r >= excl && r < excl + s) {
        unsigned int acc = excl;
        for (int i = 0; i < bpt; ++i) {
            int b = b0 + i;
            unsigned int c = gh[b];
            if (r < acc + c) {
                if (pass == 0) { state_bits[n] = (unsigned int)b; state_rank[n] = r - acc; }
                else if (pass == 1) { state_bits[n] = (state_bits[n] << 12) | (unsigned int)b; state_rank[n] = r - acc; }
                else { cutoff[n] = (state_bits[n] << 7) | (unsigned int)b; }
                break;
            }
            acc += c;
        }
    }
}

// ---------------- Apply: out = h * (key >= cutoff ? 1.0 : (1 - tau)) ----------------
__global__ __launch_bounds__(NTHREADS) void apply_kernel(const float4* __restrict__ h,
                                                         const float* __restrict__ tau,
                                                         const unsigned int* __restrict__ cutoff,
                                                         float4* __restrict__ out) {
    const int n = blockIdx.x >> 6;
    const int chunk = blockIdx.x & 63;
    const unsigned int c = cutoff[n];
    const float t = tau[0];
    const float lo = 1.0f - t;
    const size_t base = (size_t)n * F4_PER_SAMPLE + (size_t)chunk * F4_PER_BLOCK;
    const int tid = threadIdx.x;
#pragma unroll
    for (int k = 0; k < F4_PER_THREAD; ++k) {
        float4 v = h[base + k * NTHREADS + tid];
        float4 o;
        o.x = v.x * ((akey(v.x) >= c) ? 1.0f : lo);
        o.y = v.y * ((akey(v.y) >= c) ? 1.0f : lo);
        o.z = v.z * ((akey(v.z) >= c) ? 1.0f : lo);
        o.w = v.w * ((akey(v.w) >= c) ? 1.0f : lo);
        out[base + k * NTHREADS + tid] = o;
    }
}

extern "C" void kernel_launch(void* const* d_in, const int* in_sizes, int n_in,
                              void* d_out, int out_size, void* d_ws, size_t ws_size,
                              hipStream_t stream) {
    const float* h = (const float*)d_in[0];
    const float* tau = (const float*)d_in[1];
    float* out = (float*)d_out;

    const int total = in_sizes[0];
    const int N = total / CHW;              // 64

    const int k0 = (int)(0.1 * (double)CHW);                      // 52428
    const unsigned int init_rank = (unsigned int)(CHW - 1 - k0);  // 471859

    dim3 grid((unsigned)(N * BLOCKS_PER_SAMPLE)), blk(NTHREADS);

    // ---- fast path layout: hist1 | ccnt | ovfl | cutk | cand ----
    const size_t fast_words = (size_t)N * NB12 + 3 * (size_t)N + (size_t)N * CAP_PER_SAMPLE;
    if (ws_size >= fast_words * 4) {
        unsigned int* hist1 = (unsigned int*)d_ws;
        unsigned int* ccnt  = hist1 + (size_t)N * NB12;
        unsigned int* ovfl  = ccnt + N;
        unsigned int* cutk  = ovfl + N;
        unsigned int* cand  = cutk + N;

        const int zwords = N * NB12 + 2 * N;             // hist1 + ccnt + ovfl
        zero_ws<<<(zwords + NTHREADS - 1) / NTHREADS, blk, 0, stream>>>(hist1, zwords);
        hist_compact<<<grid, blk, 0, stream>>>((const float4*)h, hist1, cand, ccnt, ovfl);
        select_cand<<<N, blk, 0, stream>>>(hist1, cand, ccnt, ovfl, h, cutk, init_rank);
        apply_kernel<<<grid, blk, 0, stream>>>((const float4*)h, tau, cutk, (float4*)out);
        return;
    }

    // ---- fallback: original 3-pass path (needs ~2.2 MB ws) ----
    unsigned int* hist1 = (unsigned int*)d_ws;
    unsigned int* hist2 = hist1 + (size_t)N * NB12;
    unsigned int* hist3 = hist2 + (size_t)N * NB12;
    unsigned int* sbits = hist3 + (size_t)N * NB7;
    unsigned int* srank = sbits + N;
    unsigned int* cutk  = srank + N;
    const int zwords = 2 * N * NB12 + N * NB7 + 3 * N;

    zero_ws<<<(zwords + NTHREADS - 1) / NTHREADS, blk, 0, stream>>>(hist1, zwords);
    hist_pass1<<<grid, blk, 0, stream>>>((const float4*)h, hist1);
    select_pass<<<N, blk, 0, stream>>>(hist1, NB12, 0, sbits, srank, cutk, init_rank);
    hist_pass2<<<grid, blk, 0, stream>>>((const float4*)h, sbits, hist2);
    select_pass<<<N, blk, 0, stream>>>(hist2, NB12, 1, sbits, srank, cutk, 0u);
    hist_pass3<<<grid, blk, 0, stream>>>((const float4*)h, sbits, hist3);
    select_pass<<<N, blk, 0, stream>>>(hist3, NB7, 2, sbits, srank, cutk, 0u);
    apply_kernel<<<grid, blk, 0, stream>>>((const float4*)h, tau, cutk, (float4*)out);
}

// Round 5
// 158.793 us; speedup vs baseline: 20.2207x; 1.1597x over previous
//
#include <hip/hip_runtime.h>
#include <cstdint>
#include <cstddef>

// Problem geometry (fixed by reference setup_inputs):
//   h: (64, 512, 32, 32) fp32;  chw = 512*32*32 = 2^19
//   k0 = int(0.1 * chw) = 52428; ascending rank = chw-1-k0 = 471859
//   need = chw - rank = 52429 elements are >= cutoff
//   out = h * (|h| >= cutoff ? 1.0 : (1 - tau))
#define CHW 524288
#define F4_PER_SAMPLE (CHW / 4)            // 131072
#define BLOCKS_PER_SAMPLE 64
#define F4_PER_BLOCK (F4_PER_SAMPLE / BLOCKS_PER_SAMPLE)  // 2048
#define NTHREADS 256
#define F4_PER_THREAD (F4_PER_BLOCK / NTHREADS)           // 8
#define NB12 4096
#define NB10 1024
#define NB7  128
#define CAP_PER_SAMPLE 49152                // global candidate cap (avg ~33.4k, sd ~180)
#define LCAP 1024                           // per-block LDS cap (avg ~522, sd ~22)
// Candidate window [1.5, 1.8125), bin-aligned: bits(1.5f)=0x3FC00000.
#define WIN_LO_BIN 2040u
#define WIN_HI_BIN 2045u
#define WIN_LO_KEY (WIN_LO_BIN << 19)
#define WIN_HI_KEY (WIN_HI_BIN << 19)

__device__ __forceinline__ unsigned int akey(float x) {
    return __float_as_uint(x) & 0x7FFFFFFFu;   // monotonic key for |x|
}

// ---------------- zero workspace words ----------------
__global__ __launch_bounds__(NTHREADS) void zero_ws(unsigned int* __restrict__ p, int words) {
    int i = blockIdx.x * NTHREADS + threadIdx.x;
    if (i < words) p[i] = 0u;
}

// ---------------- find bin containing ascending rank r in lh[nbins] ----------------
// All threads participate; result in *sbin/*srem (shared). Exactly one thread writes.
__device__ __forceinline__ void find_bin(const unsigned int* lh, int nbins,
                                         unsigned int r, unsigned int* part,
                                         unsigned int* sbin, unsigned int* srem) {
    const int t = threadIdx.x;
    const int bpt = (nbins + NTHREADS - 1) / NTHREADS;
    unsigned int s = 0;
    const int b0 = t * bpt;
    for (int i = 0; i < bpt; ++i) { int b = b0 + i; if (b < nbins) s += lh[b]; }
    part[t] = s;
    __syncthreads();
    for (int off = 1; off < NTHREADS; off <<= 1) {
        unsigned int v = (t >= off) ? part[t - off] : 0u;
        __syncthreads();
        part[t] += v;
        __syncthreads();
    }
    const unsigned int excl = part[t] - s;
    if (s > 0 && r >= excl && r < excl + s) {
        unsigned int acc = excl;
        for (int i = 0; i < bpt; ++i) {
            int b = b0 + i;
            unsigned int c = (b < nbins) ? lh[b] : 0u;
            if (r < acc + c) { *sbin = (unsigned int)b; *srem = r - acc; break; }
            acc += c;
        }
    }
    __syncthreads();
}

// ============================================================================
// Pass 1 (the only full-data pass besides apply): count keys >= WIN_HI per
// sample, and compact keys in [WIN_LO, WIN_HI) into a candidate list.
// NO histogram (R4 post-mortem: 4096-bin LDS histogram atomics on Gaussian
// data = hot-bin same-address serialization, the 4x stall).
// ============================================================================
__global__ __launch_bounds__(NTHREADS) void win_compact(const float4* __restrict__ h,
                                                        unsigned int* __restrict__ cand,
                                                        unsigned int* __restrict__ ccount,
                                                        unsigned int* __restrict__ cnthi,
                                                        unsigned int* __restrict__ ovfl) {
    __shared__ unsigned int lbuf[LCAP];
    __shared__ unsigned int red[NTHREADS];
    __shared__ unsigned int lcnt, gbase;
    const int t = threadIdx.x;
    if (t == 0) lcnt = 0u;
    __syncthreads();

    const int n = blockIdx.x >> 6;
    const int chunk = blockIdx.x & 63;
    const float4* p = h + (size_t)n * F4_PER_SAMPLE + (size_t)chunk * F4_PER_BLOCK;
    const int lane = t & 63;
    unsigned int chi = 0;

#pragma unroll
    for (int k = 0; k < F4_PER_THREAD; ++k) {
        float4 v = p[k * NTHREADS + t];
        unsigned int kk[4] = { akey(v.x), akey(v.y), akey(v.z), akey(v.w) };
#pragma unroll
        for (int c = 0; c < 4; ++c) {
            unsigned int key = kk[c];
            chi += (key >= WIN_HI_KEY) ? 1u : 0u;
            bool pred = (key >= WIN_LO_KEY) & (key < WIN_HI_KEY);
            unsigned long long m = __ballot(pred);
            if (m) {
                int leader = __ffsll((long long)m) - 1;
                unsigned int base = 0;
                if (lane == leader) base = atomicAdd(&lcnt, (unsigned int)__popcll(m));
                base = __shfl(base, leader);
                if (pred) {
                    unsigned int pos = base + (unsigned int)__popcll(m & ((1ull << lane) - 1ull));
                    if (pos < LCAP) lbuf[pos] = key;
                }
            }
        }
    }

    // block-reduce chi
    red[t] = chi;
    __syncthreads();
    for (int off = NTHREADS / 2; off > 0; off >>= 1) {
        if (t < off) red[t] += red[t + off];
        __syncthreads();
    }

    const unsigned int total = lcnt;
    const unsigned int wcnt = (total < (unsigned int)LCAP) ? total : (unsigned int)LCAP;
    if (t == 0) {
        atomicAdd(&cnthi[n], red[0]);
        gbase = atomicAdd(&ccount[n], wcnt);
        if (total > (unsigned int)LCAP) atomicOr(&ovfl[n], 1u);
    }
    __syncthreads();
    const unsigned int base = gbase;
    unsigned int* mycand = cand + (size_t)n * CAP_PER_SAMPLE;
    for (unsigned int i = t; i < wcnt; i += NTHREADS) {
        unsigned int pos = base + i;
        if (pos < CAP_PER_SAMPLE) mycand[pos] = lbuf[i];
    }
}

// ============================================================================
// Per-sample select: 2-level radix (12+10 bits) over the candidate list.
// Fallback (window miss / overflow — not expected for this input): exact
// 3-level radix scanning h directly.
// ============================================================================
__global__ __launch_bounds__(NTHREADS) void select_cand(const unsigned int* __restrict__ cand,
                                                        const unsigned int* __restrict__ ccount,
                                                        const unsigned int* __restrict__ cnthi,
                                                        const unsigned int* __restrict__ ovfl,
                                                        const float* __restrict__ h,
                                                        unsigned int* __restrict__ cutk,
                                                        unsigned int need_total,
                                                        unsigned int rank) {
    __shared__ unsigned int lh[NB12];
    __shared__ unsigned int part[NTHREADS];
    __shared__ unsigned int sb1, sr1, sb2, sr2, sb3;
    const int n = blockIdx.x;
    const int t = threadIdx.x;

    const unsigned int cn  = ccount[n];
    const unsigned int chi = cnthi[n];
    const bool in_win = (ovfl[n] == 0u) && (cn <= (unsigned int)CAP_PER_SAMPLE) &&
                        (chi < need_total) && (chi + cn >= need_total);

    if (in_win) {
        const unsigned int* clist = cand + (size_t)n * CAP_PER_SAMPLE;
        // cutoff = (need_total - chi)-th largest candidate
        //        = ascending index cn - (need_total - chi)
        const unsigned int rp = cn - (need_total - chi);

        // level A: bins of (key - WIN_LO) >> 10   (range < 2560)
        for (int i = t; i < NB12; i += NTHREADS) lh[i] = 0;
        __syncthreads();
        for (unsigned int i = t; i < cn; i += NTHREADS)
            atomicAdd(&lh[(clist[i] - WIN_LO_KEY) >> 10], 1u);
        __syncthreads();
        find_bin(lh, NB12, rp, part, &sb1, &sr1);
        const unsigned int cb = sb1, r2 = sr1;

        // level B: low 10 bits among candidates in coarse bin cb
        for (int i = t; i < NB10; i += NTHREADS) lh[i] = 0;
        __syncthreads();
        for (unsigned int i = t; i < cn; i += NTHREADS) {
            unsigned int w = clist[i] - WIN_LO_KEY;
            if ((w >> 10) == cb) atomicAdd(&lh[w & 0x3FFu], 1u);
        }
        __syncthreads();
        find_bin(lh, NB10, r2, part, &sb2, &sr2);
        if (t == 0) cutk[n] = WIN_LO_KEY + (cb << 10) + sb2;
        return;
    }

    // ---------- exact fallback: 3-level radix over full sample ----------
    const float* hp = h + (size_t)n * CHW;

    // F1: top 12 bits
    for (int i = t; i < NB12; i += NTHREADS) lh[i] = 0;
    __syncthreads();
    for (unsigned int i = t; i < (unsigned int)CHW; i += NTHREADS)
        atomicAdd(&lh[akey(hp[i]) >> 19], 1u);
    __syncthreads();
    find_bin(lh, NB12, rank, part, &sb1, &sr1);
    const unsigned int b1 = sb1, r1 = sr1;

    // F2: bits 18:7 among top12 == b1
    for (int i = t; i < NB12; i += NTHREADS) lh[i] = 0;
    __syncthreads();
    for (unsigned int i = t; i < (unsigned int)CHW; i += NTHREADS) {
        unsigned int key = akey(hp[i]);
        if ((key >> 19) == b1) atomicAdd(&lh[(key >> 7) & 0xFFFu], 1u);
    }
    __syncthreads();
    find_bin(lh, NB12, r1, part, &sb2, &sr2);
    const unsigned int b2 = sb2, r2f = sr2;
    const unsigned int p24 = (b1 << 12) | b2;

    // F3: low 7 bits among top24 == p24
    for (int i = t; i < NB7; i += NTHREADS) lh[i] = 0;
    __syncthreads();
    for (unsigned int i = t; i < (unsigned int)CHW; i += NTHREADS) {
        unsigned int key = akey(hp[i]);
        if ((key >> 7) == p24) atomicAdd(&lh[key & 0x7Fu], 1u);
    }
    __syncthreads();
    find_bin(lh, NB7, r2f, part, &sb3, &sr1);
    if (t == 0) cutk[n] = (p24 << 7) | sb3;
}

// ---------------- Apply: out = h * (key >= cutoff ? 1.0 : (1 - tau)) ----------------
__global__ __launch_bounds__(NTHREADS) void apply_kernel(const float4* __restrict__ h,
                                                         const float* __restrict__ tau,
                                                         const unsigned int* __restrict__ cutoff,
                                                         float4* __restrict__ out) {
    const int n = blockIdx.x >> 6;
    const int chunk = blockIdx.x & 63;
    const unsigned int c = cutoff[n];
    const float t = tau[0];
    const float lo = 1.0f - t;
    const size_t base = (size_t)n * F4_PER_SAMPLE + (size_t)chunk * F4_PER_BLOCK;
    const int tid = threadIdx.x;
#pragma unroll
    for (int k = 0; k < F4_PER_THREAD; ++k) {
        float4 v = h[base + k * NTHREADS + tid];
        float4 o;
        o.x = v.x * ((akey(v.x) >= c) ? 1.0f : lo);
        o.y = v.y * ((akey(v.y) >= c) ? 1.0f : lo);
        o.z = v.z * ((akey(v.z) >= c) ? 1.0f : lo);
        o.w = v.w * ((akey(v.w) >= c) ? 1.0f : lo);
        out[base + k * NTHREADS + tid] = o;
    }
}

// ============================================================================
// FALLBACK PIPELINE (small d_ws): 3-pass radix select (R2 structure)
// ============================================================================
__global__ __launch_bounds__(NTHREADS) void hist_pass1(const float4* __restrict__ h,
                                                       unsigned int* __restrict__ hist) {
    __shared__ unsigned int lh[NB12];
    const int t = threadIdx.x;
    for (int i = t; i < NB12; i += NTHREADS) lh[i] = 0;
    __syncthreads();
    const int n = blockIdx.x >> 6;
    const int chunk = blockIdx.x & 63;
    const float4* p = h + (size_t)n * F4_PER_SAMPLE + (size_t)chunk * F4_PER_BLOCK;
#pragma unroll
    for (int k = 0; k < F4_PER_THREAD; ++k) {
        float4 v = p[k * NTHREADS + t];
        atomicAdd(&lh[akey(v.x) >> 19], 1u);
        atomicAdd(&lh[akey(v.y) >> 19], 1u);
        atomicAdd(&lh[akey(v.z) >> 19], 1u);
        atomicAdd(&lh[akey(v.w) >> 19], 1u);
    }
    __syncthreads();
    unsigned int* gh = hist + (size_t)n * NB12;
    for (int i = t; i < NB12; i += NTHREADS) {
        unsigned int v = lh[i];
        if (v) atomicAdd(&gh[i], v);
    }
}

__global__ __launch_bounds__(NTHREADS) void hist_pass2(const float4* __restrict__ h,
                                                       const unsigned int* __restrict__ state_bits,
                                                       unsigned int* __restrict__ hist) {
    __shared__ unsigned int lh[NB12];
    const int t = threadIdx.x;
    for (int i = t; i < NB12; i += NTHREADS) lh[i] = 0;
    __syncthreads();
    const int n = blockIdx.x >> 6;
    const int chunk = blockIdx.x & 63;
    const unsigned int b1 = state_bits[n];
    const float4* p = h + (size_t)n * F4_PER_SAMPLE + (size_t)chunk * F4_PER_BLOCK;
#pragma unroll
    for (int k = 0; k < F4_PER_THREAD; ++k) {
        float4 v = p[k * NTHREADS + t];
        unsigned int ka = akey(v.x), kb = akey(v.y), kc = akey(v.z), kd = akey(v.w);
        if ((ka >> 19) == b1) atomicAdd(&lh[(ka >> 7) & 0xFFFu], 1u);
        if ((kb >> 19) == b1) atomicAdd(&lh[(kb >> 7) & 0xFFFu], 1u);
        if ((kc >> 19) == b1) atomicAdd(&lh[(kc >> 7) & 0xFFFu], 1u);
        if ((kd >> 19) == b1) atomicAdd(&lh[(kd >> 7) & 0xFFFu], 1u);
    }
    __syncthreads();
    unsigned int* gh = hist + (size_t)n * NB12;
    for (int i = t; i < NB12; i += NTHREADS) {
        unsigned int v = lh[i];
        if (v) atomicAdd(&gh[i], v);
    }
}

__global__ __launch_bounds__(NTHREADS) void hist_pass3(const float4* __restrict__ h,
                                                       const unsigned int* __restrict__ state_bits,
                                                       unsigned int* __restrict__ hist) {
    __shared__ unsigned int lh[NB7];
    const int t = threadIdx.x;
    for (int i = t; i < NB7; i += NTHREADS) lh[i] = 0;
    __syncthreads();
    const int n = blockIdx.x >> 6;
    const int chunk = blockIdx.x & 63;
    const unsigned int p24 = state_bits[n];
    const float4* p = h + (size_t)n * F4_PER_SAMPLE + (size_t)chunk * F4_PER_BLOCK;
#pragma unroll
    for (int k = 0; k < F4_PER_THREAD; ++k) {
        float4 v = p[k * NTHREADS + t];
        unsigned int ka = akey(v.x), kb = akey(v.y), kc = akey(v.z), kd = akey(v.w);
        if ((ka >> 7) == p24) atomicAdd(&lh[ka & 0x7Fu], 1u);
        if ((kb >> 7) == p24) atomicAdd(&lh[kb & 0x7Fu], 1u);
        if ((kc >> 7) == p24) atomicAdd(&lh[kc & 0x7Fu], 1u);
        if ((kd >> 7) == p24) atomicAdd(&lh[kd & 0x7Fu], 1u);
    }
    __syncthreads();
    unsigned int* gh = hist + (size_t)n * NB7;
    for (int i = t; i < NB7; i += NTHREADS) {
        unsigned int v = lh[i];
        if (v) atomicAdd(&gh[i], v);
    }
}

__global__ __launch_bounds__(NTHREADS) void select_pass(const unsigned int* __restrict__ hist,
                                                        int nbins, int pass,
                                                        unsigned int* __restrict__ state_bits,
                                                        unsigned int* __restrict__ state_rank,
                                                        unsigned int* __restrict__ cutoff,
                                                        unsigned int init_rank) {
    __shared__ unsigned int part[NTHREADS];
    __shared__ unsigned int sbin, srem;
    const int n = blockIdx.x;
    const int t = threadIdx.x;
    const unsigned int* gh = hist + (size_t)n * nbins;
    const unsigned int r = (pass == 0) ? init_rank : state_rank[n];
    find_bin(gh, nbins, r, part, &sbin, &srem);
    if (t == 0) {
        if (pass == 0) { state_bits[n] = sbin; state_rank[n] = srem; }
        else if (pass == 1) { state_bits[n] = (state_bits[n] << 12) | sbin; state_rank[n] = srem; }
        else { cutoff[n] = (state_bits[n] << 7) | sbin; }
    }
}

extern "C" void kernel_launch(void* const* d_in, const int* in_sizes, int n_in,
                              void* d_out, int out_size, void* d_ws, size_t ws_size,
                              hipStream_t stream) {
    const float* h = (const float*)d_in[0];
    const float* tau = (const float*)d_in[1];
    float* out = (float*)d_out;

    const int total = in_sizes[0];
    const int N = total / CHW;              // 64

    const int k0 = (int)(0.1 * (double)CHW);                      // 52428
    const unsigned int init_rank = (unsigned int)(CHW - 1 - k0);  // 471859
    const unsigned int need_total = (unsigned int)CHW - init_rank; // 52429

    dim3 grid((unsigned)(N * BLOCKS_PER_SAMPLE)), blk(NTHREADS);

    // ---- fast path layout: ccnt | cnthi | ovfl | cutk | cand ----
    const size_t fast_words = 4 * (size_t)N + (size_t)N * CAP_PER_SAMPLE;
    if (ws_size >= fast_words * 4) {
        unsigned int* ccnt  = (unsigned int*)d_ws;
        unsigned int* cnthi = ccnt + N;
        unsigned int* ovfl  = cnthi + N;
        unsigned int* cutk  = ovfl + N;
        unsigned int* cand  = cutk + N;

        const int zwords = 3 * N;                        // ccnt + cnthi + ovfl
        zero_ws<<<1, blk, 0, stream>>>(ccnt, zwords);
        win_compact<<<grid, blk, 0, stream>>>((const float4*)h, cand, ccnt, cnthi, ovfl);
        select_cand<<<N, blk, 0, stream>>>(cand, ccnt, cnthi, ovfl, h, cutk,
                                           need_total, init_rank);
        apply_kernel<<<grid, blk, 0, stream>>>((const float4*)h, tau, cutk, (float4*)out);
        return;
    }

    // ---- fallback pipeline: original 3-pass path (needs ~2.2 MB ws) ----
    unsigned int* hist1 = (unsigned int*)d_ws;
    unsigned int* hist2 = hist1 + (size_t)N * NB12;
    unsigned int* hist3 = hist2 + (size_t)N * NB12;
    unsigned int* sbits = hist3 + (size_t)N * NB7;
    unsigned int* srank = sbits + N;
    unsigned int* cutk  = srank + N;
    const int zwords = 2 * N * NB12 + N * NB7 + 3 * N;

    zero_ws<<<(zwords + NTHREADS - 1) / NTHREADS, blk, 0, stream>>>(hist1, zwords);
    hist_pass1<<<grid, blk, 0, stream>>>((const float4*)h, hist1);
    select_pass<<<N, blk, 0, stream>>>(hist1, NB12, 0, sbits, srank, cutk, init_rank);
    hist_pass2<<<grid, blk, 0, stream>>>((const float4*)h, sbits, hist2);
    select_pass<<<N, blk, 0, stream>>>(hist2, NB12, 1, sbits, srank, cutk, 0u);
    hist_pass3<<<grid, blk, 0, stream>>>((const float4*)h, sbits, hist3);
    select_pass<<<N, blk, 0, stream>>>(hist3, NB7, 2, sbits, srank, cutk, 0u);
    apply_kernel<<<grid, blk, 0, stream>>>((const float4*)h, tau, cutk, (float4*)out);
}

// Round 6
// 151.466 us; speedup vs baseline: 21.1989x; 1.0484x over previous
//
#include <hip/hip_runtime.h>
#include <cstdint>
#include <cstddef>

// Problem geometry (fixed by reference setup_inputs):
//   h: (64, 512, 32, 32) fp32;  chw = 512*32*32 = 2^19
//   k0 = int(0.1 * chw) = 52428; ascending rank = chw-1-k0 = 471859
//   need = chw - rank = 52429 elements are >= cutoff
//   out = h * (|h| >= cutoff ? 1.0 : (1 - tau))
#define CHW 524288
#define F4_PER_SAMPLE (CHW / 4)            // 131072
#define BLOCKS_PER_SAMPLE 64
#define F4_PER_BLOCK (F4_PER_SAMPLE / BLOCKS_PER_SAMPLE)  // 2048
#define NTHREADS 256
#define F4_PER_THREAD (F4_PER_BLOCK / NTHREADS)           // 8
#define ELEMS_PER_THREAD (F4_PER_THREAD * 4)              // 32
#define NB12 4096
#define NB10 1024
#define NB7  128
#define CAP_PER_SAMPLE 49152                // global candidate cap (mean ~33.4k, sd ~180)
#define LCAP 1024                           // per-block LDS cap (mean ~130, sd ~11)
// Candidate window [1.5, 1.8125), bin-aligned: bits(1.5f)=0x3FC00000.
#define WIN_LO_BIN 2040u
#define WIN_HI_BIN 2045u
#define WIN_LO_KEY (WIN_LO_BIN << 19)
#define WIN_HI_KEY (WIN_HI_BIN << 19)

__device__ __forceinline__ unsigned int akey(float x) {
    return __float_as_uint(x) & 0x7FFFFFFFu;   // monotonic key for |x|
}

// ---------------- zero workspace words ----------------
__global__ __launch_bounds__(NTHREADS) void zero_ws(unsigned int* __restrict__ p, int words) {
    int i = blockIdx.x * NTHREADS + threadIdx.x;
    if (i < words) p[i] = 0u;
}

// ---------------- find bin containing ascending rank r in lh[nbins] ----------------
__device__ __forceinline__ void find_bin(const unsigned int* lh, int nbins,
                                         unsigned int r, unsigned int* part,
                                         unsigned int* sbin, unsigned int* srem) {
    const int t = threadIdx.x;
    const int bpt = (nbins + NTHREADS - 1) / NTHREADS;
    unsigned int s = 0;
    const int b0 = t * bpt;
    for (int i = 0; i < bpt; ++i) { int b = b0 + i; if (b < nbins) s += lh[b]; }
    part[t] = s;
    __syncthreads();
    for (int off = 1; off < NTHREADS; off <<= 1) {
        unsigned int v = (t >= off) ? part[t - off] : 0u;
        __syncthreads();
        part[t] += v;
        __syncthreads();
    }
    const unsigned int excl = part[t] - s;
    if (s > 0 && r >= excl && r < excl + s) {
        unsigned int acc = excl;
        for (int i = 0; i < bpt; ++i) {
            int b = b0 + i;
            unsigned int c = (b < nbins) ? lh[b] : 0u;
            if (r < acc + c) { *sbin = (unsigned int)b; *srem = r - acc; break; }
            acc += c;
        }
    }
    __syncthreads();
}

// ============================================================================
// Pass 1: register-staged count + compact. NO ballots, NO per-element atomics
// (R5 post-mortem: the ballot->ffs->LDS-atomic->shfl dependent chain per
// element-slot was the stall). Per-thread count -> block scan -> private
// LDS offsets -> one global atomic per block.
// ============================================================================
__global__ __launch_bounds__(NTHREADS) void win_compact(const float4* __restrict__ h,
                                                        unsigned int* __restrict__ cand,
                                                        unsigned int* __restrict__ ccount,
                                                        unsigned int* __restrict__ cnthi,
                                                        unsigned int* __restrict__ ovfl) {
    __shared__ unsigned int lbuf[LCAP];
    __shared__ unsigned int part[NTHREADS];
    __shared__ unsigned int gbase;
    const int t = threadIdx.x;
    const int n = blockIdx.x >> 6;
    const int chunk = blockIdx.x & 63;
    const float4* p = h + (size_t)n * F4_PER_SAMPLE + (size_t)chunk * F4_PER_BLOCK;

    // ---- load 8 float4 -> 32 keys in registers ----
    float4 vv[F4_PER_THREAD];
#pragma unroll
    for (int k = 0; k < F4_PER_THREAD; ++k) vv[k] = p[k * NTHREADS + t];
    unsigned int keys[ELEMS_PER_THREAD];
#pragma unroll
    for (int k = 0; k < F4_PER_THREAD; ++k) {
        keys[4 * k + 0] = akey(vv[k].x);
        keys[4 * k + 1] = akey(vv[k].y);
        keys[4 * k + 2] = akey(vv[k].z);
        keys[4 * k + 3] = akey(vv[k].w);
    }

    // ---- per-thread counts (pure VALU) ----
    unsigned int chi = 0, cwin = 0;
#pragma unroll
    for (int j = 0; j < ELEMS_PER_THREAD; ++j) {
        chi  += (keys[j] >= WIN_HI_KEY) ? 1u : 0u;
        cwin += (keys[j] >= WIN_LO_KEY && keys[j] < WIN_HI_KEY) ? 1u : 0u;
    }

    // ---- block inclusive scan of cwin -> private base ----
    part[t] = cwin;
    __syncthreads();
    for (int off = 1; off < NTHREADS; off <<= 1) {
        unsigned int v = (t >= off) ? part[t - off] : 0u;
        __syncthreads();
        part[t] += v;
        __syncthreads();
    }
    const unsigned int total = part[NTHREADS - 1];
    unsigned int pos = part[t] - cwin;          // exclusive prefix
    __syncthreads();

    // ---- write candidates at private offsets (no atomics) ----
#pragma unroll
    for (int j = 0; j < ELEMS_PER_THREAD; ++j) {
        unsigned int key = keys[j];
        if (key >= WIN_LO_KEY && key < WIN_HI_KEY) {
            if (pos < (unsigned int)LCAP) lbuf[pos] = key;
            ++pos;
        }
    }

    // ---- block reduce chi (reuse part) ----
    part[t] = chi;
    __syncthreads();
    for (int off = NTHREADS / 2; off > 0; off >>= 1) {
        if (t < off) part[t] += part[t + off];
        __syncthreads();
    }

    const unsigned int wcnt = (total < (unsigned int)LCAP) ? total : (unsigned int)LCAP;
    if (t == 0) {
        atomicAdd(&cnthi[n], part[0]);
        gbase = atomicAdd(&ccount[n], wcnt);
        if (total > (unsigned int)LCAP) atomicOr(&ovfl[n], 1u);
    }
    __syncthreads();
    const unsigned int base = gbase;
    unsigned int* mycand = cand + (size_t)n * CAP_PER_SAMPLE;
    for (unsigned int i = t; i < wcnt; i += NTHREADS) {
        unsigned int gpos = base + i;
        if (gpos < (unsigned int)CAP_PER_SAMPLE) mycand[gpos] = lbuf[i];
    }
}

// ============================================================================
// Per-sample select: 2-level radix (12+10 bits of key-WIN_LO) over candidates.
// Fallback (window miss / overflow — never for this input): exact 3-level
// radix scanning h directly.
// ============================================================================
__global__ __launch_bounds__(NTHREADS) void select_cand(const unsigned int* __restrict__ cand,
                                                        const unsigned int* __restrict__ ccount,
                                                        const unsigned int* __restrict__ cnthi,
                                                        const unsigned int* __restrict__ ovfl,
                                                        const float* __restrict__ h,
                                                        unsigned int* __restrict__ cutk,
                                                        unsigned int need_total,
                                                        unsigned int rank) {
    __shared__ unsigned int lh[NB12];
    __shared__ unsigned int part[NTHREADS];
    __shared__ unsigned int sb1, sr1, sb2, sr2, sb3;
    const int n = blockIdx.x;
    const int t = threadIdx.x;

    const unsigned int cn  = ccount[n];
    const unsigned int chi = cnthi[n];
    const bool in_win = (ovfl[n] == 0u) && (cn <= (unsigned int)CAP_PER_SAMPLE) &&
                        (chi < need_total) && (chi + cn >= need_total);

    if (in_win) {
        const unsigned int* clist = cand + (size_t)n * CAP_PER_SAMPLE;
        const unsigned int rp = cn - (need_total - chi);   // ascending rank in cands

        // level A: bins of (key - WIN_LO) >> 10  (range < 2560)
        for (int i = t; i < NB12; i += NTHREADS) lh[i] = 0;
        __syncthreads();
        for (unsigned int i = t; i < cn; i += NTHREADS)
            atomicAdd(&lh[(clist[i] - WIN_LO_KEY) >> 10], 1u);
        __syncthreads();
        find_bin(lh, NB12, rp, part, &sb1, &sr1);
        const unsigned int cb = sb1, r2 = sr1;

        // level B: low 10 bits among candidates in coarse bin cb
        for (int i = t; i < NB10; i += NTHREADS) lh[i] = 0;
        __syncthreads();
        for (unsigned int i = t; i < cn; i += NTHREADS) {
            unsigned int w = clist[i] - WIN_LO_KEY;
            if ((w >> 10) == cb) atomicAdd(&lh[w & 0x3FFu], 1u);
        }
        __syncthreads();
        find_bin(lh, NB10, r2, part, &sb2, &sr2);
        if (t == 0) cutk[n] = WIN_LO_KEY + (cb << 10) + sb2;
        return;
    }

    // ---------- exact fallback: 3-level radix over full sample ----------
    const float* hp = h + (size_t)n * CHW;

    for (int i = t; i < NB12; i += NTHREADS) lh[i] = 0;
    __syncthreads();
    for (unsigned int i = t; i < (unsigned int)CHW; i += NTHREADS)
        atomicAdd(&lh[akey(hp[i]) >> 19], 1u);
    __syncthreads();
    find_bin(lh, NB12, rank, part, &sb1, &sr1);
    const unsigned int b1 = sb1, r1 = sr1;

    for (int i = t; i < NB12; i += NTHREADS) lh[i] = 0;
    __syncthreads();
    for (unsigned int i = t; i < (unsigned int)CHW; i += NTHREADS) {
        unsigned int key = akey(hp[i]);
        if ((key >> 19) == b1) atomicAdd(&lh[(key >> 7) & 0xFFFu], 1u);
    }
    __syncthreads();
    find_bin(lh, NB12, r1, part, &sb2, &sr2);
    const unsigned int b2 = sb2, r2f = sr2;
    const unsigned int p24 = (b1 << 12) | b2;

    for (int i = t; i < NB7; i += NTHREADS) lh[i] = 0;
    __syncthreads();
    for (unsigned int i = t; i < (unsigned int)CHW; i += NTHREADS) {
        unsigned int key = akey(hp[i]);
        if ((key >> 7) == p24) atomicAdd(&lh[key & 0x7Fu], 1u);
    }
    __syncthreads();
    find_bin(lh, NB7, r2f, part, &sb3, &sr1);
    if (t == 0) cutk[n] = (p24 << 7) | sb3;
}

// ---------------- Apply: out = h * (key >= cutoff ? 1.0 : (1 - tau)) ----------------
__global__ __launch_bounds__(NTHREADS) void apply_kernel(const float4* __restrict__ h,
                                                         const float* __restrict__ tau,
                                                         const unsigned int* __restrict__ cutoff,
                                                         float4* __restrict__ out) {
    const int n = blockIdx.x >> 6;
    const int chunk = blockIdx.x & 63;
    const unsigned int c = cutoff[n];
    const float t = tau[0];
    const float lo = 1.0f - t;
    const size_t base = (size_t)n * F4_PER_SAMPLE + (size_t)chunk * F4_PER_BLOCK;
    const int tid = threadIdx.x;
#pragma unroll
    for (int k = 0; k < F4_PER_THREAD; ++k) {
        float4 v = h[base + k * NTHREADS + tid];
        float4 o;
        o.x = v.x * ((akey(v.x) >= c) ? 1.0f : lo);
        o.y = v.y * ((akey(v.y) >= c) ? 1.0f : lo);
        o.z = v.z * ((akey(v.z) >= c) ? 1.0f : lo);
        o.w = v.w * ((akey(v.w) >= c) ? 1.0f : lo);
        out[base + k * NTHREADS + tid] = o;
    }
}

// ============================================================================
// FALLBACK PIPELINE (small d_ws): 3-pass radix select (R2 structure)
// ============================================================================
__global__ __launch_bounds__(NTHREADS) void hist_pass1(const float4* __restrict__ h,
                                                       unsigned int* __restrict__ hist) {
    __shared__ unsigned int lh[NB12];
    const int t = threadIdx.x;
    for (int i = t; i < NB12; i += NTHREADS) lh[i] = 0;
    __syncthreads();
    const int n = blockIdx.x >> 6;
    const int chunk = blockIdx.x & 63;
    const float4* p = h + (size_t)n * F4_PER_SAMPLE + (size_t)chunk * F4_PER_BLOCK;
#pragma unroll
    for (int k = 0; k < F4_PER_THREAD; ++k) {
        float4 v = p[k * NTHREADS + t];
        atomicAdd(&lh[akey(v.x) >> 19], 1u);
        atomicAdd(&lh[akey(v.y) >> 19], 1u);
        atomicAdd(&lh[akey(v.z) >> 19], 1u);
        atomicAdd(&lh[akey(v.w) >> 19], 1u);
    }
    __syncthreads();
    unsigned int* gh = hist + (size_t)n * NB12;
    for (int i = t; i < NB12; i += NTHREADS) {
        unsigned int v = lh[i];
        if (v) atomicAdd(&gh[i], v);
    }
}

__global__ __launch_bounds__(NTHREADS) void hist_pass2(const float4* __restrict__ h,
                                                       const unsigned int* __restrict__ state_bits,
                                                       unsigned int* __restrict__ hist) {
    __shared__ unsigned int lh[NB12];
    const int t = threadIdx.x;
    for (int i = t; i < NB12; i += NTHREADS) lh[i] = 0;
    __syncthreads();
    const int n = blockIdx.x >> 6;
    const int chunk = blockIdx.x & 63;
    const unsigned int b1 = state_bits[n];
    const float4* p = h + (size_t)n * F4_PER_SAMPLE + (size_t)chunk * F4_PER_BLOCK;
#pragma unroll
    for (int k = 0; k < F4_PER_THREAD; ++k) {
        float4 v = p[k * NTHREADS + t];
        unsigned int ka = akey(v.x), kb = akey(v.y), kc = akey(v.z), kd = akey(v.w);
        if ((ka >> 19) == b1) atomicAdd(&lh[(ka >> 7) & 0xFFFu], 1u);
        if ((kb >> 19) == b1) atomicAdd(&lh[(kb >> 7) & 0xFFFu], 1u);
        if ((kc >> 19) == b1) atomicAdd(&lh[(kc >> 7) & 0xFFFu], 1u);
        if ((kd >> 19) == b1) atomicAdd(&lh[(kd >> 7) & 0xFFFu], 1u);
    }
    __syncthreads();
    unsigned int* gh = hist + (size_t)n * NB12;
    for (int i = t; i < NB12; i += NTHREADS) {
        unsigned int v = lh[i];
        if (v) atomicAdd(&gh[i], v);
    }
}

__global__ __launch_bounds__(NTHREADS) void hist_pass3(const float4* __restrict__ h,
                                                       const unsigned int* __restrict__ state_bits,
                                                       unsigned int* __restrict__ hist) {
    __shared__ unsigned int lh[NB7];
    const int t = threadIdx.x;
    for (int i = t; i < NB7; i += NTHREADS) lh[i] = 0;
    __syncthreads();
    const int n = blockIdx.x >> 6;
    const int chunk = blockIdx.x & 63;
    const unsigned int p24 = state_bits[n];
    const float4* p = h + (size_t)n * F4_PER_SAMPLE + (size_t)chunk * F4_PER_BLOCK;
#pragma unroll
    for (int k = 0; k < F4_PER_THREAD; ++k) {
        float4 v = p[k * NTHREADS + t];
        unsigned int ka = akey(v.x), kb = akey(v.y), kc = akey(v.z), kd = akey(v.w);
        if ((ka >> 7) == p24) atomicAdd(&lh[ka & 0x7Fu], 1u);
        if ((kb >> 7) == p24) atomicAdd(&lh[kb & 0x7Fu], 1u);
        if ((kc >> 7) == p24) atomicAdd(&lh[kc & 0x7Fu], 1u);
        if ((kd >> 7) == p24) atomicAdd(&lh[kd & 0x7Fu], 1u);
    }
    __syncthreads();
    unsigned int* gh = hist + (size_t)n * NB7;
    for (int i = t; i < NB7; i += NTHREADS) {
        unsigned int v = lh[i];
        if (v) atomicAdd(&gh[i], v);
    }
}

__global__ __launch_bounds__(NTHREADS) void select_pass(const unsigned int* __restrict__ hist,
                                                        int nbins, int pass,
                                                        unsigned int* __restrict__ state_bits,
                                                        unsigned int* __restrict__ state_rank,
                                                        unsigned int* __restrict__ cutoff,
                                                        unsigned int init_rank) {
    __shared__ unsigned int part[NTHREADS];
    __shared__ unsigned int sbin, srem;
    const int n = blockIdx.x;
    const int t = threadIdx.x;
    const unsigned int* gh = hist + (size_t)n * nbins;
    const unsigned int r = (pass == 0) ? init_rank : state_rank[n];
    find_bin(gh, nbins, r, part, &sbin, &srem);
    if (t == 0) {
        if (pass == 0) { state_bits[n] = sbin; state_rank[n] = srem; }
        else if (pass == 1) { state_bits[n] = (state_bits[n] << 12) | sbin; state_rank[n] = srem; }
        else { cutoff[n] = (state_bits[n] << 7) | sbin; }
    }
}

extern "C" void kernel_launch(void* const* d_in, const int* in_sizes, int n_in,
                              void* d_out, int out_size, void* d_ws, size_t ws_size,
                              hipStream_t stream) {
    const float* h = (const float*)d_in[0];
    const float* tau = (const float*)d_in[1];
    float* out = (float*)d_out;

    const int total = in_sizes[0];
    const int N = total / CHW;              // 64

    const int k0 = (int)(0.1 * (double)CHW);                       // 52428
    const unsigned int init_rank = (unsigned int)(CHW - 1 - k0);   // 471859
    const unsigned int need_total = (unsigned int)CHW - init_rank; // 52429

    dim3 grid((unsigned)(N * BLOCKS_PER_SAMPLE)), blk(NTHREADS);

    // ---- fast path layout: ccnt | cnthi | ovfl | cutk | cand ----
    const size_t fast_words = 4 * (size_t)N + (size_t)N * CAP_PER_SAMPLE;
    if (ws_size >= fast_words * 4) {
        unsigned int* ccnt  = (unsigned int*)d_ws;
        unsigned int* cnthi = ccnt + N;
        unsigned int* ovfl  = cnthi + N;
        unsigned int* cutk  = ovfl + N;
        unsigned int* cand  = cutk + N;

        const int zwords = 3 * N;                        // ccnt + cnthi + ovfl
        zero_ws<<<1, blk, 0, stream>>>(ccnt, zwords);
        win_compact<<<grid, blk, 0, stream>>>((const float4*)h, cand, ccnt, cnthi, ovfl);
        select_cand<<<N, blk, 0, stream>>>(cand, ccnt, cnthi, ovfl, h, cutk,
                                           need_total, init_rank);
        apply_kernel<<<grid, blk, 0, stream>>>((const float4*)h, tau, cutk, (float4*)out);
        return;
    }

    // ---- fallback pipeline: original 3-pass path (needs ~2.2 MB ws) ----
    unsigned int* hist1 = (unsigned int*)d_ws;
    unsigned int* hist2 = hist1 + (size_t)N * NB12;
    unsigned int* hist3 = hist2 + (size_t)N * NB12;
    unsigned int* sbits = hist3 + (size_t)N * NB7;
    unsigned int* srank = sbits + N;
    unsigned int* cutk  = srank + N;
    const int zwords = 2 * N * NB12 + N * NB7 + 3 * N;

    zero_ws<<<(zwords + NTHREADS - 1) / NTHREADS, blk, 0, stream>>>(hist1, zwords);
    hist_pass1<<<grid, blk, 0, stream>>>((const float4*)h, hist1);
    select_pass<<<N, blk, 0, stream>>>(hist1, NB12, 0, sbits, srank, cutk, init_rank);
    hist_pass2<<<grid, blk, 0, stream>>>((const float4*)h, sbits, hist2);
    select_pass<<<N, blk, 0, stream>>>(hist2, NB12, 1, sbits, srank, cutk, 0u);
    hist_pass3<<<grid, blk, 0, stream>>>((const float4*)h, sbits, hist3);
    select_pass<<<N, blk, 0, stream>>>(hist3, NB7, 2, sbits, srank, cutk, 0u);
    apply_kernel<<<grid, blk, 0, stream>>>((const float4*)h, tau, cutk, (float4*)out);
}

// Round 7
// 103.185 us; speedup vs baseline: 31.1179x; 1.4679x over previous
//
#include <hip/hip_runtime.h>
#include <cstdint>
#include <cstddef>

// Problem geometry (fixed by reference setup_inputs):
//   h: (64, 512, 32, 32) fp32;  chw = 512*32*32 = 2^19
//   k0 = int(0.1 * chw) = 52428; ascending rank = chw-1-k0 = 471859
//   need = chw - rank = 52429 elements are >= cutoff
//   out = h * (|h| >= cutoff ? 1.0 : (1 - tau))
#define CHW 524288
#define F4_PER_SAMPLE (CHW / 4)            // 131072
#define BLOCKS_PER_SAMPLE 64
#define F4_PER_BLOCK (F4_PER_SAMPLE / BLOCKS_PER_SAMPLE)  // 2048 float4 = 32 KiB
#define NTHREADS 256
#define F4_PER_THREAD (F4_PER_BLOCK / NTHREADS)           // 8
#define ELEMS_PER_THREAD (F4_PER_THREAD * 4)              // 32
#define NB12 4096
#define NB10 1024
#define NB7  128
#define LCAP 1024        // per-block candidate segment cap (mean ~520, sd ~22 -> 23 sigma)
#define NTH2 1024        // select_cand block size (16 waves -> latency hiding)
#define DCAP 34816       // dense LDS candidate cap (mean ~33.3k, sd ~177 -> 8.5 sigma)
#define NBA  2560        // level-A bins: window span (5<<19)>>10
// Candidate window [1.5, 1.8125), bin-aligned: bits(1.5f)=0x3FC00000.
#define WIN_LO_BIN 2040u
#define WIN_HI_BIN 2045u
#define WIN_LO_KEY (WIN_LO_BIN << 19)
#define WIN_HI_KEY (WIN_HI_BIN << 19)

typedef float f32x4 __attribute__((ext_vector_type(4)));

__device__ __forceinline__ unsigned int akey(float x) {
    return __float_as_uint(x) & 0x7FFFFFFFu;   // monotonic key for |x|
}

// ---------------- zero workspace words (fallback pipeline only) ----------------
__global__ __launch_bounds__(NTHREADS) void zero_ws(unsigned int* __restrict__ p, int words) {
    int i = blockIdx.x * NTHREADS + threadIdx.x;
    if (i < words) p[i] = 0u;
}

// ---------------- find bin containing ascending rank r in lh[nbins] ----------------
template<int NT>
__device__ __forceinline__ void find_binT(const unsigned int* lh, int nbins,
                                          unsigned int r, unsigned int* part,
                                          unsigned int* sbin, unsigned int* srem) {
    const int t = threadIdx.x;
    const int bpt = (nbins + NT - 1) / NT;
    unsigned int s = 0;
    const int b0 = t * bpt;
    for (int i = 0; i < bpt; ++i) { int b = b0 + i; if (b < nbins) s += lh[b]; }
    part[t] = s;
    __syncthreads();
    for (int off = 1; off < NT; off <<= 1) {
        unsigned int v = (t >= off) ? part[t - off] : 0u;
        __syncthreads();
        part[t] += v;
        __syncthreads();
    }
    const unsigned int excl = part[t] - s;
    if (s > 0 && r >= excl && r < excl + s) {
        unsigned int acc = excl;
        for (int i = 0; i < bpt; ++i) {
            int b = b0 + i;
            unsigned int c = (b < nbins) ? lh[b] : 0u;
            if (r < acc + c) { *sbin = (unsigned int)b; *srem = r - acc; break; }
            acc += c;
        }
    }
    __syncthreads();
}

// ============================================================================
// Pass 1: register-staged count + compact into PER-BLOCK private segments.
// No global atomics, nothing needs pre-zeroing (R6 post-mortem follow-up).
// ============================================================================
__global__ __launch_bounds__(NTHREADS) void win_compact(const float4* __restrict__ h,
                                                        unsigned int* __restrict__ cand,
                                                        unsigned int* __restrict__ bcnt,
                                                        unsigned int* __restrict__ bchi) {
    __shared__ unsigned int lbuf[LCAP];
    __shared__ unsigned int part[NTHREADS];
    const int t = threadIdx.x;
    const int bid = blockIdx.x;
    const float4* p = h + (size_t)bid * F4_PER_BLOCK;

    // ---- load 8 float4 -> 32 keys in registers ----
    float4 vv[F4_PER_THREAD];
#pragma unroll
    for (int k = 0; k < F4_PER_THREAD; ++k) vv[k] = p[k * NTHREADS + t];
    unsigned int keys[ELEMS_PER_THREAD];
#pragma unroll
    for (int k = 0; k < F4_PER_THREAD; ++k) {
        keys[4 * k + 0] = akey(vv[k].x);
        keys[4 * k + 1] = akey(vv[k].y);
        keys[4 * k + 2] = akey(vv[k].z);
        keys[4 * k + 3] = akey(vv[k].w);
    }

    // ---- per-thread counts (pure VALU) ----
    unsigned int chi = 0, cwin = 0;
#pragma unroll
    for (int j = 0; j < ELEMS_PER_THREAD; ++j) {
        chi  += (keys[j] >= WIN_HI_KEY) ? 1u : 0u;
        cwin += (keys[j] >= WIN_LO_KEY && keys[j] < WIN_HI_KEY) ? 1u : 0u;
    }

    // ---- block inclusive scan of cwin -> private base ----
    part[t] = cwin;
    __syncthreads();
    for (int off = 1; off < NTHREADS; off <<= 1) {
        unsigned int v = (t >= off) ? part[t - off] : 0u;
        __syncthreads();
        part[t] += v;
        __syncthreads();
    }
    const unsigned int total = part[NTHREADS - 1];
    unsigned int pos = part[t] - cwin;          // exclusive prefix
    __syncthreads();

    // ---- write candidates at private offsets (no atomics) ----
#pragma unroll
    for (int j = 0; j < ELEMS_PER_THREAD; ++j) {
        unsigned int key = keys[j];
        if (key >= WIN_LO_KEY && key < WIN_HI_KEY) {
            if (pos < (unsigned int)LCAP) lbuf[pos] = key;
            ++pos;
        }
    }

    // ---- block reduce chi (reuse part) ----
    part[t] = chi;
    __syncthreads();
    for (int off = NTHREADS / 2; off > 0; off >>= 1) {
        if (t < off) part[t] += part[t + off];
        __syncthreads();
    }

    if (t == 0) { bcnt[bid] = total; bchi[bid] = part[0]; }
    const unsigned int wcnt = (total < (unsigned int)LCAP) ? total : (unsigned int)LCAP;
    unsigned int* mycand = cand + (size_t)bid * LCAP;
    for (unsigned int i = t; i < wcnt; i += NTHREADS) mycand[i] = lbuf[i];
}

// ============================================================================
// Per-sample select: stage all candidates into a dense LDS buffer (one
// coalesced read), then 2-level radix (10+10 bits of key-WIN_LO) in LDS.
// 1024 threads = 16 waves (R6 post-mortem: old 256-thread version was
// latency-bound at 1 wave/SIMD doing serial scalar global loads, ~80 us).
// Fallback (window miss / overflow): exact 3-level radix scanning h.
// ============================================================================
__global__ __launch_bounds__(NTH2) void select_cand(const unsigned int* __restrict__ cand,
                                                    const unsigned int* __restrict__ bcnt,
                                                    const unsigned int* __restrict__ bchi,
                                                    const float* __restrict__ h,
                                                    unsigned int* __restrict__ cutk,
                                                    unsigned int need_total,
                                                    unsigned int rank) {
    __shared__ unsigned int dense[DCAP];     // 136 KB
    __shared__ unsigned int lh[NBA];         // 10 KB
    __shared__ unsigned int part[NTH2];      // 4 KB
    __shared__ unsigned int cnts[64], excl[64], chired[64];
    __shared__ unsigned int sb1, sr1, sb2, sr2, sb3, sr3;
    __shared__ unsigned int s_ovf, s_cn;
    const int n = blockIdx.x;
    const int t = threadIdx.x;

    if (t == 0) s_ovf = 0u;
    if (t < 64) { cnts[t] = bcnt[(n << 6) + t]; chired[t] = bchi[(n << 6) + t]; }
    __syncthreads();
    if (t < 64 && cnts[t] > (unsigned int)LCAP) atomicOr(&s_ovf, 1u);
    // scan segment counts (64 entries) in part[0..63]
    if (t < 64) part[t] = cnts[t];
    __syncthreads();
    for (int off = 1; off < 64; off <<= 1) {
        unsigned int v = (t >= off && t < 64) ? part[t - off] : 0u;
        __syncthreads();
        if (t < 64) part[t] += v;
        __syncthreads();
    }
    if (t < 64) excl[t] = part[t] - cnts[t];
    if (t == 63) s_cn = part[63];
    __syncthreads();
    // reduce chi over 64 entries
    for (int off = 32; off > 0; off >>= 1) {
        if (t < off) chired[t] += chired[t + off];
        __syncthreads();
    }
    const unsigned int cn  = s_cn;
    const unsigned int chi = chired[0];
    const bool in_win = (s_ovf == 0u) && (cn <= (unsigned int)DCAP) &&
                        (chi < need_total) && (chi + cn >= need_total);

    if (in_win) {
        // ---- stage all segments into dense LDS (coalesced) ----
        for (int c = 0; c < 64; ++c) {
            const unsigned int bc  = cnts[c];
            const unsigned int off = excl[c];
            const unsigned int* src = cand + (size_t)((n << 6) + c) * LCAP;
            for (unsigned int i = t; i < bc; i += NTH2) dense[off + i] = src[i];
        }
        __syncthreads();
        const unsigned int rp = cn - (need_total - chi);   // ascending rank in cands

        // ---- level A: (key - WIN_LO) >> 10, 2560 bins ----
        for (int i = t; i < NBA; i += NTH2) lh[i] = 0;
        __syncthreads();
        for (unsigned int i = t; i < cn; i += NTH2)
            atomicAdd(&lh[(dense[i] - WIN_LO_KEY) >> 10], 1u);
        __syncthreads();
        find_binT<NTH2>(lh, NBA, rp, part, &sb1, &sr1);
        const unsigned int cb = sb1, r2 = sr1;

        // ---- level B: low 10 bits within coarse bin cb ----
        for (int i = t; i < NB10; i += NTH2) lh[i] = 0;
        __syncthreads();
        for (unsigned int i = t; i < cn; i += NTH2) {
            unsigned int w = dense[i] - WIN_LO_KEY;
            if ((w >> 10) == cb) atomicAdd(&lh[w & 0x3FFu], 1u);
        }
        __syncthreads();
        find_binT<NTH2>(lh, NB10, r2, part, &sb2, &sr2);
        if (t == 0) cutk[n] = WIN_LO_KEY + (cb << 10) + sb2;
        return;
    }

    // ---------- exact fallback: 3-level radix over full sample (hist in dense) ----------
    const float* hp = h + (size_t)n * CHW;
    unsigned int* lhF = dense;               // DCAP >= 4096

    for (int i = t; i < NB12; i += NTH2) lhF[i] = 0;
    __syncthreads();
    for (unsigned int i = t; i < (unsigned int)CHW; i += NTH2)
        atomicAdd(&lhF[akey(hp[i]) >> 19], 1u);
    __syncthreads();
    find_binT<NTH2>(lhF, NB12, rank, part, &sb1, &sr1);
    const unsigned int b1 = sb1, r1 = sr1;

    for (int i = t; i < NB12; i += NTH2) lhF[i] = 0;
    __syncthreads();
    for (unsigned int i = t; i < (unsigned int)CHW; i += NTH2) {
        unsigned int key = akey(hp[i]);
        if ((key >> 19) == b1) atomicAdd(&lhF[(key >> 7) & 0xFFFu], 1u);
    }
    __syncthreads();
    find_binT<NTH2>(lhF, NB12, r1, part, &sb2, &sr2);
    const unsigned int b2 = sb2, r2f = sr2;
    const unsigned int p24 = (b1 << 12) | b2;

    for (int i = t; i < NB7; i += NTH2) lhF[i] = 0;
    __syncthreads();
    for (unsigned int i = t; i < (unsigned int)CHW; i += NTH2) {
        unsigned int key = akey(hp[i]);
        if ((key >> 7) == p24) atomicAdd(&lhF[key & 0x7Fu], 1u);
    }
    __syncthreads();
    find_binT<NTH2>(lhF, NB7, r2f, part, &sb3, &sr3);
    if (t == 0) cutk[n] = (p24 << 7) | sb3;
}

// ---------------- Apply: out = h * (key >= cutoff ? 1.0 : (1 - tau)) ----------------
// Non-temporal stores: keep h resident in L3 for its (second) read.
__global__ __launch_bounds__(NTHREADS) void apply_kernel(const f32x4* __restrict__ h,
                                                         const float* __restrict__ tau,
                                                         const unsigned int* __restrict__ cutoff,
                                                         f32x4* __restrict__ out) {
    const int n = blockIdx.x >> 6;
    const int chunk = blockIdx.x & 63;
    const unsigned int c = cutoff[n];
    const float t = tau[0];
    const float lo = 1.0f - t;
    const size_t base = (size_t)n * F4_PER_SAMPLE + (size_t)chunk * F4_PER_BLOCK;
    const int tid = threadIdx.x;
#pragma unroll
    for (int k = 0; k < F4_PER_THREAD; ++k) {
        f32x4 v = h[base + k * NTHREADS + tid];
        f32x4 o;
        o.x = v.x * ((akey(v.x) >= c) ? 1.0f : lo);
        o.y = v.y * ((akey(v.y) >= c) ? 1.0f : lo);
        o.z = v.z * ((akey(v.z) >= c) ? 1.0f : lo);
        o.w = v.w * ((akey(v.w) >= c) ? 1.0f : lo);
        __builtin_nontemporal_store(o, &out[base + k * NTHREADS + tid]);
    }
}

// ============================================================================
// FALLBACK PIPELINE (small d_ws): 3-pass radix select (R2 structure)
// ============================================================================
__global__ __launch_bounds__(NTHREADS) void hist_pass1(const float4* __restrict__ h,
                                                       unsigned int* __restrict__ hist) {
    __shared__ unsigned int lh[NB12];
    const int t = threadIdx.x;
    for (int i = t; i < NB12; i += NTHREADS) lh[i] = 0;
    __syncthreads();
    const float4* p = h + (size_t)blockIdx.x * F4_PER_BLOCK;
    const int n = blockIdx.x >> 6;
#pragma unroll
    for (int k = 0; k < F4_PER_THREAD; ++k) {
        float4 v = p[k * NTHREADS + t];
        atomicAdd(&lh[akey(v.x) >> 19], 1u);
        atomicAdd(&lh[akey(v.y) >> 19], 1u);
        atomicAdd(&lh[akey(v.z) >> 19], 1u);
        atomicAdd(&lh[akey(v.w) >> 19], 1u);
    }
    __syncthreads();
    unsigned int* gh = hist + (size_t)n * NB12;
    for (int i = t; i < NB12; i += NTHREADS) {
        unsigned int v = lh[i];
        if (v) atomicAdd(&gh[i], v);
    }
}

__global__ __launch_bounds__(NTHREADS) void hist_pass2(const float4* __restrict__ h,
                                                       const unsigned int* __restrict__ state_bits,
                                                       unsigned int* __restrict__ hist) {
    __shared__ unsigned int lh[NB12];
    const int t = threadIdx.x;
    for (int i = t; i < NB12; i += NTHREADS) lh[i] = 0;
    __syncthreads();
    const int n = blockIdx.x >> 6;
    const unsigned int b1 = state_bits[n];
    const float4* p = h + (size_t)blockIdx.x * F4_PER_BLOCK;
#pragma unroll
    for (int k = 0; k < F4_PER_THREAD; ++k) {
        float4 v = p[k * NTHREADS + t];
        unsigned int ka = akey(v.x), kb = akey(v.y), kc = akey(v.z), kd = akey(v.w);
        if ((ka >> 19) == b1) atomicAdd(&lh[(ka >> 7) & 0xFFFu], 1u);
        if ((kb >> 19) == b1) atomicAdd(&lh[(kb >> 7) & 0xFFFu], 1u);
        if ((kc >> 19) == b1) atomicAdd(&lh[(kc >> 7) & 0xFFFu], 1u);
        if ((kd >> 19) == b1) atomicAdd(&lh[(kd >> 7) & 0xFFFu], 1u);
    }
    __syncthreads();
    unsigned int* gh = hist + (size_t)n * NB12;
    for (int i = t; i < NB12; i += NTHREADS) {
        unsigned int v = lh[i];
        if (v) atomicAdd(&gh[i], v);
    }
}

__global__ __launch_bounds__(NTHREADS) void hist_pass3(const float4* __restrict__ h,
                                                       const unsigned int* __restrict__ state_bits,
                                                       unsigned int* __restrict__ hist) {
    __shared__ unsigned int lh[NB7];
    const int t = threadIdx.x;
    for (int i = t; i < NB7; i += NTHREADS) lh[i] = 0;
    __syncthreads();
    const int n = blockIdx.x >> 6;
    const unsigned int p24 = state_bits[n];
    const float4* p = h + (size_t)blockIdx.x * F4_PER_BLOCK;
#pragma unroll
    for (int k = 0; k < F4_PER_THREAD; ++k) {
        float4 v = p[k * NTHREADS + t];
        unsigned int ka = akey(v.x), kb = akey(v.y), kc = akey(v.z), kd = akey(v.w);
        if ((ka >> 7) == p24) atomicAdd(&lh[ka & 0x7Fu], 1u);
        if ((kb >> 7) == p24) atomicAdd(&lh[kb & 0x7Fu], 1u);
        if ((kc >> 7) == p24) atomicAdd(&lh[kc & 0x7Fu], 1u);
        if ((kd >> 7) == p24) atomicAdd(&lh[kd & 0x7Fu], 1u);
    }
    __syncthreads();
    unsigned int* gh = hist + (size_t)n * NB7;
    for (int i = t; i < NB7; i += NTHREADS) {
        unsigned int v = lh[i];
        if (v) atomicAdd(&gh[i], v);
    }
}

__global__ __launch_bounds__(NTHREADS) void select_pass(const unsigned int* __restrict__ hist,
                                                        int nbins, int pass,
                                                        unsigned int* __restrict__ state_bits,
                                                        unsigned int* __restrict__ state_rank,
                                                        unsigned int* __restrict__ cutoff,
                                                        unsigned int init_rank) {
    __shared__ unsigned int part[NTHREADS];
    __shared__ unsigned int sbin, srem;
    const int n = blockIdx.x;
    const int t = threadIdx.x;
    const unsigned int* gh = hist + (size_t)n * nbins;
    const unsigned int r = (pass == 0) ? init_rank : state_rank[n];
    find_binT<NTHREADS>(gh, nbins, r, part, &sbin, &srem);
    if (t == 0) {
        if (pass == 0) { state_bits[n] = sbin; state_rank[n] = srem; }
        else if (pass == 1) { state_bits[n] = (state_bits[n] << 12) | sbin; state_rank[n] = srem; }
        else { cutoff[n] = (state_bits[n] << 7) | sbin; }
    }
}

extern "C" void kernel_launch(void* const* d_in, const int* in_sizes, int n_in,
                              void* d_out, int out_size, void* d_ws, size_t ws_size,
                              hipStream_t stream) {
    const float* h = (const float*)d_in[0];
    const float* tau = (const float*)d_in[1];
    float* out = (float*)d_out;

    const int total = in_sizes[0];
    const int N = total / CHW;              // 64
    const int NBLK = N * BLOCKS_PER_SAMPLE; // 4096

    const int k0 = (int)(0.1 * (double)CHW);                       // 52428
    const unsigned int init_rank = (unsigned int)(CHW - 1 - k0);   // 471859
    const unsigned int need_total = (unsigned int)CHW - init_rank; // 52429

    dim3 grid((unsigned)NBLK), blk(NTHREADS);

    // ---- fast path layout: bcnt[NBLK] | bchi[NBLK] | cutk[N] | cand[NBLK*LCAP] ----
    const size_t fast_words = 2 * (size_t)NBLK + (size_t)N + (size_t)NBLK * LCAP;
    if (ws_size >= fast_words * 4) {
        unsigned int* bcnt = (unsigned int*)d_ws;
        unsigned int* bchi = bcnt + NBLK;
        unsigned int* cutk = bchi + NBLK;
        unsigned int* cand = cutk + N;

        win_compact<<<grid, blk, 0, stream>>>((const float4*)h, cand, bcnt, bchi);
        select_cand<<<N, NTH2, 0, stream>>>(cand, bcnt, bchi, h, cutk,
                                            need_total, init_rank);
        apply_kernel<<<grid, blk, 0, stream>>>((const f32x4*)h, tau, cutk, (f32x4*)out);
        return;
    }

    // ---- fallback pipeline: original 3-pass path (needs ~2.2 MB ws) ----
    unsigned int* hist1 = (unsigned int*)d_ws;
    unsigned int* hist2 = hist1 + (size_t)N * NB12;
    unsigned int* hist3 = hist2 + (size_t)N * NB12;
    unsigned int* sbits = hist3 + (size_t)N * NB7;
    unsigned int* srank = sbits + N;
    unsigned int* cutk  = srank + N;
    const int zwords = 2 * N * NB12 + N * NB7 + 3 * N;

    zero_ws<<<(zwords + NTHREADS - 1) / NTHREADS, blk, 0, stream>>>(hist1, zwords);
    hist_pass1<<<grid, blk, 0, stream>>>((const float4*)h, hist1);
    select_pass<<<N, blk, 0, stream>>>(hist1, NB12, 0, sbits, srank, cutk, init_rank);
    hist_pass2<<<grid, blk, 0, stream>>>((const float4*)h, sbits, hist2);
    select_pass<<<N, blk, 0, stream>>>(hist2, NB12, 1, sbits, srank, cutk, 0u);
    hist_pass3<<<grid, blk, 0, stream>>>((const float4*)h, sbits, hist3);
    select_pass<<<N, blk, 0, stream>>>(hist3, NB7, 2, sbits, srank, cutk, 0u);
    apply_kernel<<<grid, blk, 0, stream>>>((const f32x4*)h, tau, cutk, (f32x4*)out);
}

// Round 8
// 98.131 us; speedup vs baseline: 32.7206x; 1.0515x over previous
//
#include <hip/hip_runtime.h>
#include <cstdint>
#include <cstddef>

// Problem geometry (fixed by reference setup_inputs):
//   h: (64, 512, 32, 32) fp32;  chw = 512*32*32 = 2^19
//   k0 = int(0.1 * chw) = 52428; ascending rank = chw-1-k0 = 471859
//   need = chw - rank = 52429 elements are >= cutoff
//   out = h * (|h| >= cutoff ? 1.0 : (1 - tau))
#define CHW 524288
#define F4_PER_SAMPLE (CHW / 4)            // 131072
#define BLOCKS_PER_SAMPLE 64
#define F4_PER_BLOCK (F4_PER_SAMPLE / BLOCKS_PER_SAMPLE)  // 2048 float4 = 32 KiB
#define NTHREADS 256
#define F4_PER_THREAD (F4_PER_BLOCK / NTHREADS)           // 8
#define ELEMS_PER_THREAD (F4_PER_THREAD * 4)              // 32
#define NB12 4096
#define NB10 1024
#define NB7  128
#define LCAP 512         // per-block candidate cap (mean ~219, sd ~14.6 -> 20 sigma)
#define NTH2 1024        // select_cand block size (16 waves)
#define DCAP 16384       // dense LDS candidate cap (mean ~14.0k, sd ~117 -> 20 sigma)
#define NBA  1024        // level-A bins: window span (2<<19)>>10
// Candidate window [1.5625, 1.6875), bin-aligned (bin = key>>19; 2041..2042).
// cutoff ~ 1.645 +- 0.004 (5-sigma span [1.625,1.665]) -> >=20-sigma margins.
#define WIN_LO_BIN 2041u
#define WIN_HI_BIN 2043u
#define WIN_LO_KEY (WIN_LO_BIN << 19)
#define WIN_HI_KEY (WIN_HI_BIN << 19)

typedef float f32x4 __attribute__((ext_vector_type(4)));

__device__ __forceinline__ unsigned int akey(float x) {
    return __float_as_uint(x) & 0x7FFFFFFFu;   // monotonic key for |x|
}

// ---------------- zero workspace words (fallback pipeline only) ----------------
__global__ __launch_bounds__(NTHREADS) void zero_ws(unsigned int* __restrict__ p, int words) {
    int i = blockIdx.x * NTHREADS + threadIdx.x;
    if (i < words) p[i] = 0u;
}

// ---------------- find bin containing ascending rank r in lh[nbins] ----------------
template<int NT>
__device__ __forceinline__ void find_binT(const unsigned int* lh, int nbins,
                                          unsigned int r, unsigned int* part,
                                          unsigned int* sbin, unsigned int* srem) {
    const int t = threadIdx.x;
    const int bpt = (nbins + NT - 1) / NT;
    unsigned int s = 0;
    const int b0 = t * bpt;
    for (int i = 0; i < bpt; ++i) { int b = b0 + i; if (b < nbins) s += lh[b]; }
    part[t] = s;
    __syncthreads();
    for (int off = 1; off < NT; off <<= 1) {
        unsigned int v = (t >= off) ? part[t - off] : 0u;
        __syncthreads();
        part[t] += v;
        __syncthreads();
    }
    const unsigned int excl = part[t] - s;
    if (s > 0 && r >= excl && r < excl + s) {
        unsigned int acc = excl;
        for (int i = 0; i < bpt; ++i) {
            int b = b0 + i;
            unsigned int c = (b < nbins) ? lh[b] : 0u;
            if (r < acc + c) { *sbin = (unsigned int)b; *srem = r - acc; break; }
            acc += c;
        }
    }
    __syncthreads();
}

// ============================================================================
// Pass 1: register-staged count + compact into PER-BLOCK private segments.
// Wave-level shfl scan (2 barriers total; R7 post-mortem: 16-barrier
// Hillis-Steele was serial overhead on every 32KB chunk).
// ============================================================================
__global__ __launch_bounds__(NTHREADS) void win_compact(const float4* __restrict__ h,
                                                        unsigned int* __restrict__ cand,
                                                        unsigned int* __restrict__ bcnt,
                                                        unsigned int* __restrict__ bchi) {
    __shared__ unsigned int lbuf[LCAP];
    __shared__ unsigned int wtot[4], wchi[4];
    const int t = threadIdx.x;
    const int lane = t & 63;
    const int w = t >> 6;
    const int bid = blockIdx.x;
    const float4* p = h + (size_t)bid * F4_PER_BLOCK;

    // ---- load 8 float4 -> 32 keys in registers ----
    float4 vv[F4_PER_THREAD];
#pragma unroll
    for (int k = 0; k < F4_PER_THREAD; ++k) vv[k] = p[k * NTHREADS + t];
    unsigned int keys[ELEMS_PER_THREAD];
#pragma unroll
    for (int k = 0; k < F4_PER_THREAD; ++k) {
        keys[4 * k + 0] = akey(vv[k].x);
        keys[4 * k + 1] = akey(vv[k].y);
        keys[4 * k + 2] = akey(vv[k].z);
        keys[4 * k + 3] = akey(vv[k].w);
    }

    // ---- per-thread counts (pure VALU) ----
    unsigned int chi = 0, cwin = 0;
#pragma unroll
    for (int j = 0; j < ELEMS_PER_THREAD; ++j) {
        chi  += (keys[j] >= WIN_HI_KEY) ? 1u : 0u;
        cwin += (keys[j] >= WIN_LO_KEY && keys[j] < WIN_HI_KEY) ? 1u : 0u;
    }

    // ---- wave inclusive scan of cwin (shfl, no LDS) ----
    unsigned int inc = cwin;
#pragma unroll
    for (int off = 1; off < 64; off <<= 1) {
        unsigned int v = __shfl_up(inc, off);
        if (lane >= off) inc += v;
    }
    // ---- wave reduce chi ----
    unsigned int wc = chi;
#pragma unroll
    for (int off = 32; off > 0; off >>= 1) wc += __shfl_xor(wc, off);

    if (lane == 63) wtot[w] = inc;
    if (lane == 0)  wchi[w] = wc;
    __syncthreads();

    unsigned int wbase = 0;
#pragma unroll
    for (int i = 0; i < 4; ++i) if (i < w) wbase += wtot[i];
    const unsigned int total  = wtot[0] + wtot[1] + wtot[2] + wtot[3];
    const unsigned int chitot = wchi[0] + wchi[1] + wchi[2] + wchi[3];
    unsigned int pos = wbase + inc - cwin;     // exclusive prefix across block

    // ---- write candidates at private offsets (no atomics) ----
#pragma unroll
    for (int j = 0; j < ELEMS_PER_THREAD; ++j) {
        unsigned int key = keys[j];
        if (key >= WIN_LO_KEY && key < WIN_HI_KEY) {
            if (pos < (unsigned int)LCAP) lbuf[pos] = key;
            ++pos;
        }
    }
    __syncthreads();

    if (t == 0) { bcnt[bid] = total; bchi[bid] = chitot; }
    const unsigned int wcnt = (total < (unsigned int)LCAP) ? total : (unsigned int)LCAP;
    unsigned int* mycand = cand + (size_t)bid * LCAP;
    for (unsigned int i = t; i < wcnt; i += NTHREADS) mycand[i] = lbuf[i];
}

// ============================================================================
// Per-sample select: stage candidates into dense LDS, 2-level radix
// (10+10 bits of key-WIN_LO). 1024 threads = 16 waves.
// Fallback (window miss / overflow): exact 3-level radix scanning h.
// ============================================================================
__global__ __launch_bounds__(NTH2) void select_cand(const unsigned int* __restrict__ cand,
                                                    const unsigned int* __restrict__ bcnt,
                                                    const unsigned int* __restrict__ bchi,
                                                    const float* __restrict__ h,
                                                    unsigned int* __restrict__ cutk,
                                                    unsigned int need_total,
                                                    unsigned int rank) {
    __shared__ unsigned int dense[DCAP];     // 64 KB
    __shared__ unsigned int lh[NBA];         // 4 KB
    __shared__ unsigned int part[NTH2];      // 4 KB
    __shared__ unsigned int cnts[64], excl[64], chired[64];
    __shared__ unsigned int sb1, sr1, sb2, sr2, sb3, sr3;
    __shared__ unsigned int s_ovf, s_cn;
    const int n = blockIdx.x;
    const int t = threadIdx.x;

    if (t == 0) s_ovf = 0u;
    if (t < 64) { cnts[t] = bcnt[(n << 6) + t]; chired[t] = bchi[(n << 6) + t]; }
    __syncthreads();
    if (t < 64 && cnts[t] > (unsigned int)LCAP) atomicOr(&s_ovf, 1u);
    if (t < 64) part[t] = cnts[t];
    __syncthreads();
    for (int off = 1; off < 64; off <<= 1) {
        unsigned int v = (t >= off && t < 64) ? part[t - off] : 0u;
        __syncthreads();
        if (t < 64) part[t] += v;
        __syncthreads();
    }
    if (t < 64) excl[t] = part[t] - cnts[t];
    if (t == 63) s_cn = part[63];
    __syncthreads();
    for (int off = 32; off > 0; off >>= 1) {
        if (t < off) chired[t] += chired[t + off];
        __syncthreads();
    }
    const unsigned int cn  = s_cn;
    const unsigned int chi = chired[0];
    const bool in_win = (s_ovf == 0u) && (cn <= (unsigned int)DCAP) &&
                        (chi < need_total) && (chi + cn >= need_total);

    if (in_win) {
        // ---- stage all segments into dense LDS (coalesced) ----
        for (int c = 0; c < 64; ++c) {
            const unsigned int bc  = cnts[c];
            const unsigned int off = excl[c];
            const unsigned int* src = cand + (size_t)((n << 6) + c) * LCAP;
            for (unsigned int i = t; i < bc; i += NTH2) dense[off + i] = src[i];
        }
        __syncthreads();
        const unsigned int rp = cn - (need_total - chi);   // ascending rank in cands

        // ---- level A: (key - WIN_LO) >> 10, 1024 bins ----
        for (int i = t; i < NBA; i += NTH2) lh[i] = 0;
        __syncthreads();
        for (unsigned int i = t; i < cn; i += NTH2)
            atomicAdd(&lh[(dense[i] - WIN_LO_KEY) >> 10], 1u);
        __syncthreads();
        find_binT<NTH2>(lh, NBA, rp, part, &sb1, &sr1);
        const unsigned int cb = sb1, r2 = sr1;

        // ---- level B: low 10 bits within coarse bin cb ----
        for (int i = t; i < NB10; i += NTH2) lh[i] = 0;
        __syncthreads();
        for (unsigned int i = t; i < cn; i += NTH2) {
            unsigned int wv = dense[i] - WIN_LO_KEY;
            if ((wv >> 10) == cb) atomicAdd(&lh[wv & 0x3FFu], 1u);
        }
        __syncthreads();
        find_binT<NTH2>(lh, NB10, r2, part, &sb2, &sr2);
        if (t == 0) cutk[n] = WIN_LO_KEY + (cb << 10) + sb2;
        return;
    }

    // ---------- exact fallback: 3-level radix over full sample ----------
    const float* hp = h + (size_t)n * CHW;
    unsigned int* lhF = dense;               // DCAP >= 4096

    for (int i = t; i < NB12; i += NTH2) lhF[i] = 0;
    __syncthreads();
    for (unsigned int i = t; i < (unsigned int)CHW; i += NTH2)
        atomicAdd(&lhF[akey(hp[i]) >> 19], 1u);
    __syncthreads();
    find_binT<NTH2>(lhF, NB12, rank, part, &sb1, &sr1);
    const unsigned int b1 = sb1, r1 = sr1;

    for (int i = t; i < NB12; i += NTH2) lhF[i] = 0;
    __syncthreads();
    for (unsigned int i = t; i < (unsigned int)CHW; i += NTH2) {
        unsigned int key = akey(hp[i]);
        if ((key >> 19) == b1) atomicAdd(&lhF[(key >> 7) & 0xFFFu], 1u);
    }
    __syncthreads();
    find_binT<NTH2>(lhF, NB12, r1, part, &sb2, &sr2);
    const unsigned int b2 = sb2, r2f = sr2;
    const unsigned int p24 = (b1 << 12) | b2;

    for (int i = t; i < NB7; i += NTH2) lhF[i] = 0;
    __syncthreads();
    for (unsigned int i = t; i < (unsigned int)CHW; i += NTH2) {
        unsigned int key = akey(hp[i]);
        if ((key >> 7) == p24) atomicAdd(&lhF[key & 0x7Fu], 1u);
    }
    __syncthreads();
    find_binT<NTH2>(lhF, NB7, r2f, part, &sb3, &sr3);
    if (t == 0) cutk[n] = (p24 << 7) | sb3;
}

// ---------------- Apply: out = h * (key >= cutoff ? 1.0 : (1 - tau)) ----------------
// Non-temporal stores: keep h resident in L3 for re-reads.
__global__ __launch_bounds__(NTHREADS) void apply_kernel(const f32x4* __restrict__ h,
                                                         const float* __restrict__ tau,
                                                         const unsigned int* __restrict__ cutoff,
                                                         f32x4* __restrict__ out) {
    const int n = blockIdx.x >> 6;
    const int chunk = blockIdx.x & 63;
    const unsigned int c = cutoff[n];
    const float t = tau[0];
    const float lo = 1.0f - t;
    const size_t base = (size_t)n * F4_PER_SAMPLE + (size_t)chunk * F4_PER_BLOCK;
    const int tid = threadIdx.x;
#pragma unroll
    for (int k = 0; k < F4_PER_THREAD; ++k) {
        f32x4 v = h[base + k * NTHREADS + tid];
        f32x4 o;
        o.x = v.x * ((akey(v.x) >= c) ? 1.0f : lo);
        o.y = v.y * ((akey(v.y) >= c) ? 1.0f : lo);
        o.z = v.z * ((akey(v.z) >= c) ? 1.0f : lo);
        o.w = v.w * ((akey(v.w) >= c) ? 1.0f : lo);
        __builtin_nontemporal_store(o, &out[base + k * NTHREADS + tid]);
    }
}

// ============================================================================
// FALLBACK PIPELINE (small d_ws): 3-pass radix select (R2 structure)
// ============================================================================
__global__ __launch_bounds__(NTHREADS) void hist_pass1(const float4* __restrict__ h,
                                                       unsigned int* __restrict__ hist) {
    __shared__ unsigned int lh[NB12];
    const int t = threadIdx.x;
    for (int i = t; i < NB12; i += NTHREADS) lh[i] = 0;
    __syncthreads();
    const float4* p = h + (size_t)blockIdx.x * F4_PER_BLOCK;
    const int n = blockIdx.x >> 6;
#pragma unroll
    for (int k = 0; k < F4_PER_THREAD; ++k) {
        float4 v = p[k * NTHREADS + t];
        atomicAdd(&lh[akey(v.x) >> 19], 1u);
        atomicAdd(&lh[akey(v.y) >> 19], 1u);
        atomicAdd(&lh[akey(v.z) >> 19], 1u);
        atomicAdd(&lh[akey(v.w) >> 19], 1u);
    }
    __syncthreads();
    unsigned int* gh = hist + (size_t)n * NB12;
    for (int i = t; i < NB12; i += NTHREADS) {
        unsigned int v = lh[i];
        if (v) atomicAdd(&gh[i], v);
    }
}

__global__ __launch_bounds__(NTHREADS) void hist_pass2(const float4* __restrict__ h,
                                                       const unsigned int* __restrict__ state_bits,
                                                       unsigned int* __restrict__ hist) {
    __shared__ unsigned int lh[NB12];
    const int t = threadIdx.x;
    for (int i = t; i < NB12; i += NTHREADS) lh[i] = 0;
    __syncthreads();
    const int n = blockIdx.x >> 6;
    const unsigned int b1 = state_bits[n];
    const float4* p = h + (size_t)blockIdx.x * F4_PER_BLOCK;
#pragma unroll
    for (int k = 0; k < F4_PER_THREAD; ++k) {
        float4 v = p[k * NTHREADS + t];
        unsigned int ka = akey(v.x), kb = akey(v.y), kc = akey(v.z), kd = akey(v.w);
        if ((ka >> 19) == b1) atomicAdd(&lh[(ka >> 7) & 0xFFFu], 1u);
        if ((kb >> 19) == b1) atomicAdd(&lh[(kb >> 7) & 0xFFFu], 1u);
        if ((kc >> 19) == b1) atomicAdd(&lh[(kc >> 7) & 0xFFFu], 1u);
        if ((kd >> 19) == b1) atomicAdd(&lh[(kd >> 7) & 0xFFFu], 1u);
    }
    __syncthreads();
    unsigned int* gh = hist + (size_t)n * NB12;
    for (int i = t; i < NB12; i += NTHREADS) {
        unsigned int v = lh[i];
        if (v) atomicAdd(&gh[i], v);
    }
}

__global__ __launch_bounds__(NTHREADS) void hist_pass3(const float4* __restrict__ h,
                                                       const unsigned int* __restrict__ state_bits,
                                                       unsigned int* __restrict__ hist) {
    __shared__ unsigned int lh[NB7];
    const int t = threadIdx.x;
    for (int i = t; i < NB7; i += NTHREADS) lh[i] = 0;
    __syncthreads();
    const int n = blockIdx.x >> 6;
    const unsigned int p24 = state_bits[n];
    const float4* p = h + (size_t)blockIdx.x * F4_PER_BLOCK;
#pragma unroll
    for (int k = 0; k < F4_PER_THREAD; ++k) {
        float4 v = p[k * NTHREADS + t];
        unsigned int ka = akey(v.x), kb = akey(v.y), kc = akey(v.z), kd = akey(v.w);
        if ((ka >> 7) == p24) atomicAdd(&lh[ka & 0x7Fu], 1u);
        if ((kb >> 7) == p24) atomicAdd(&lh[kb & 0x7Fu], 1u);
        if ((kc >> 7) == p24) atomicAdd(&lh[kc & 0x7Fu], 1u);
        if ((kd >> 7) == p24) atomicAdd(&lh[kd & 0x7Fu], 1u);
    }
    __syncthreads();
    unsigned int* gh = hist + (size_t)n * NB7;
    for (int i = t; i < NB7; i += NTHREADS) {
        unsigned int v = lh[i];
        if (v) atomicAdd(&gh[i], v);
    }
}

__global__ __launch_bounds__(NTHREADS) void select_pass(const unsigned int* __restrict__ hist,
                                                        int nbins, int pass,
                                                        unsigned int* __restrict__ state_bits,
                                                        unsigned int* __restrict__ state_rank,
                                                        unsigned int* __restrict__ cutoff,
                                                        unsigned int init_rank) {
    __shared__ unsigned int part[NTHREADS];
    __shared__ unsigned int sbin, srem;
    const int n = blockIdx.x;
    const int t = threadIdx.x;
    const unsigned int* gh = hist + (size_t)n * nbins;
    const unsigned int r = (pass == 0) ? init_rank : state_rank[n];
    find_binT<NTHREADS>(gh, nbins, r, part, &sbin, &srem);
    if (t == 0) {
        if (pass == 0) { state_bits[n] = sbin; state_rank[n] = srem; }
        else if (pass == 1) { state_bits[n] = (state_bits[n] << 12) | sbin; state_rank[n] = srem; }
        else { cutoff[n] = (state_bits[n] << 7) | sbin; }
    }
}

extern "C" void kernel_launch(void* const* d_in, const int* in_sizes, int n_in,
                              void* d_out, int out_size, void* d_ws, size_t ws_size,
                              hipStream_t stream) {
    const float* h = (const float*)d_in[0];
    const float* tau = (const float*)d_in[1];
    float* out = (float*)d_out;

    const int total = in_sizes[0];
    const int N = total / CHW;              // 64
    const int NBLK = N * BLOCKS_PER_SAMPLE; // 4096

    const int k0 = (int)(0.1 * (double)CHW);                       // 52428
    const unsigned int init_rank = (unsigned int)(CHW - 1 - k0);   // 471859
    const unsigned int need_total = (unsigned int)CHW - init_rank; // 52429

    dim3 grid((unsigned)NBLK), blk(NTHREADS);

    // ---- fast path layout: bcnt[NBLK] | bchi[NBLK] | cutk[N] | cand[NBLK*LCAP] ----
    const size_t fast_words = 2 * (size_t)NBLK + (size_t)N + (size_t)NBLK * LCAP;
    if (ws_size >= fast_words * 4) {
        unsigned int* bcnt = (unsigned int*)d_ws;
        unsigned int* bchi = bcnt + NBLK;
        unsigned int* cutk = bchi + NBLK;
        unsigned int* cand = cutk + N;

        win_compact<<<grid, blk, 0, stream>>>((const float4*)h, cand, bcnt, bchi);
        select_cand<<<N, NTH2, 0, stream>>>(cand, bcnt, bchi, h, cutk,
                                            need_total, init_rank);
        apply_kernel<<<grid, blk, 0, stream>>>((const f32x4*)h, tau, cutk, (f32x4*)out);
        return;
    }

    // ---- fallback pipeline: original 3-pass path (needs ~2.2 MB ws) ----
    unsigned int* hist1 = (unsigned int*)d_ws;
    unsigned int* hist2 = hist1 + (size_t)N * NB12;
    unsigned int* hist3 = hist2 + (size_t)N * NB12;
    unsigned int* sbits = hist3 + (size_t)N * NB7;
    unsigned int* srank = sbits + N;
    unsigned int* cutk  = srank + N;
    const int zwords = 2 * N * NB12 + N * NB7 + 3 * N;

    zero_ws<<<(zwords + NTHREADS - 1) / NTHREADS, blk, 0, stream>>>(hist1, zwords);
    hist_pass1<<<grid, blk, 0, stream>>>((const float4*)h, hist1);
    select_pass<<<N, blk, 0, stream>>>(hist1, NB12, 0, sbits, srank, cutk, init_rank);
    hist_pass2<<<grid, blk, 0, stream>>>((const float4*)h, sbits, hist2);
    select_pass<<<N, blk, 0, stream>>>(hist2, NB12, 1, sbits, srank, cutk, 0u);
    hist_pass3<<<grid, blk, 0, stream>>>((const float4*)h, sbits, hist3);
    select_pass<<<N, blk, 0, stream>>>(hist3, NB7, 2, sbits, srank, cutk, 0u);
    apply_kernel<<<grid, blk, 0, stream>>>((const f32x4*)h, tau, cutk, (f32x4*)out);
}

// Round 9
// 80.815 us; speedup vs baseline: 39.7318x; 1.2143x over previous
//
#include <hip/hip_runtime.h>
#include <cstdint>
#include <cstddef>

// Problem geometry (fixed by reference setup_inputs):
//   h: (64, 512, 32, 32) fp32;  chw = 512*32*32 = 2^19
//   k0 = int(0.1 * chw) = 52428; ascending rank = chw-1-k0 = 471859
//   need = chw - rank = 52429 elements are >= cutoff
//   out = h * (|h| >= cutoff ? 1.0 : (1 - tau))
#define CHW 524288
#define F4_PER_SAMPLE (CHW / 4)            // 131072
#define BLOCKS_PER_SAMPLE 64
#define F4_PER_BLOCK (F4_PER_SAMPLE / BLOCKS_PER_SAMPLE)  // 2048 float4 = 32 KiB
#define NTHREADS 256
#define F4_PER_THREAD (F4_PER_BLOCK / NTHREADS)           // 8
#define ELEMS_PER_THREAD (F4_PER_THREAD * 4)              // 32
#define NB12 4096
#define NB10 1024
#define NB7  128
#define LCAP 512         // per-block candidate cap (mean ~219, sd ~14.6 -> 20 sigma)
#define NTH2 1024        // select_cand block size (16 waves)
#define DCAP 16384       // dense LDS candidate cap (mean ~14.0k, sd ~117 -> 20 sigma)
#define NBA  1024        // level-A bins: window span (2<<19)>>10
// Candidate window [1.5625, 1.6875), bin-aligned (bin = key>>19; 2041..2042).
// cutoff ~ 1.645 +- 0.004 (5-sigma span [1.625,1.665]) -> >=20-sigma margins.
#define WIN_LO_BIN 2041u
#define WIN_HI_BIN 2043u
#define WIN_LO_KEY (WIN_LO_BIN << 19)
#define WIN_HI_KEY (WIN_HI_BIN << 19)

typedef float f32x4 __attribute__((ext_vector_type(4)));

__device__ __forceinline__ unsigned int akey(float x) {
    return __float_as_uint(x) & 0x7FFFFFFFu;   // monotonic key for |x|
}

// ---------------- zero workspace words (fallback pipeline only) ----------------
__global__ __launch_bounds__(NTHREADS) void zero_ws(unsigned int* __restrict__ p, int words) {
    int i = blockIdx.x * NTHREADS + threadIdx.x;
    if (i < words) p[i] = 0u;
}

// ---------------- find bin containing ascending rank r in lh[nbins] ----------------
template<int NT>
__device__ __forceinline__ void find_binT(const unsigned int* lh, int nbins,
                                          unsigned int r, unsigned int* part,
                                          unsigned int* sbin, unsigned int* srem) {
    const int t = threadIdx.x;
    const int bpt = (nbins + NT - 1) / NT;
    unsigned int s = 0;
    const int b0 = t * bpt;
    for (int i = 0; i < bpt; ++i) { int b = b0 + i; if (b < nbins) s += lh[b]; }
    part[t] = s;
    __syncthreads();
    for (int off = 1; off < NT; off <<= 1) {
        unsigned int v = (t >= off) ? part[t - off] : 0u;
        __syncthreads();
        part[t] += v;
        __syncthreads();
    }
    const unsigned int excl = part[t] - s;
    if (s > 0 && r >= excl && r < excl + s) {
        unsigned int acc = excl;
        for (int i = 0; i < bpt; ++i) {
            int b = b0 + i;
            unsigned int c = (b < nbins) ? lh[b] : 0u;
            if (r < acc + c) { *sbin = (unsigned int)b; *srem = r - acc; break; }
            acc += c;
        }
    }
    __syncthreads();
}

// ============================================================================
// Pass 1: register-staged count + compact into PER-BLOCK private segments.
// Wave-level shfl scan (2 barriers total).
// ============================================================================
__global__ __launch_bounds__(NTHREADS) void win_compact(const float4* __restrict__ h,
                                                        unsigned int* __restrict__ cand,
                                                        unsigned int* __restrict__ bcnt,
                                                        unsigned int* __restrict__ bchi) {
    __shared__ unsigned int lbuf[LCAP];
    __shared__ unsigned int wtot[4], wchi[4];
    const int t = threadIdx.x;
    const int lane = t & 63;
    const int w = t >> 6;
    const int bid = blockIdx.x;
    const float4* p = h + (size_t)bid * F4_PER_BLOCK;

    // ---- load 8 float4 -> 32 keys in registers ----
    float4 vv[F4_PER_THREAD];
#pragma unroll
    for (int k = 0; k < F4_PER_THREAD; ++k) vv[k] = p[k * NTHREADS + t];
    unsigned int keys[ELEMS_PER_THREAD];
#pragma unroll
    for (int k = 0; k < F4_PER_THREAD; ++k) {
        keys[4 * k + 0] = akey(vv[k].x);
        keys[4 * k + 1] = akey(vv[k].y);
        keys[4 * k + 2] = akey(vv[k].z);
        keys[4 * k + 3] = akey(vv[k].w);
    }

    // ---- per-thread counts (pure VALU) ----
    unsigned int chi = 0, cwin = 0;
#pragma unroll
    for (int j = 0; j < ELEMS_PER_THREAD; ++j) {
        chi  += (keys[j] >= WIN_HI_KEY) ? 1u : 0u;
        cwin += (keys[j] >= WIN_LO_KEY && keys[j] < WIN_HI_KEY) ? 1u : 0u;
    }

    // ---- wave inclusive scan of cwin (shfl, no LDS) ----
    unsigned int inc = cwin;
#pragma unroll
    for (int off = 1; off < 64; off <<= 1) {
        unsigned int v = __shfl_up(inc, off);
        if (lane >= off) inc += v;
    }
    // ---- wave reduce chi ----
    unsigned int wc = chi;
#pragma unroll
    for (int off = 32; off > 0; off >>= 1) wc += __shfl_xor(wc, off);

    if (lane == 63) wtot[w] = inc;
    if (lane == 0)  wchi[w] = wc;
    __syncthreads();

    unsigned int wbase = 0;
#pragma unroll
    for (int i = 0; i < 4; ++i) if (i < w) wbase += wtot[i];
    const unsigned int total  = wtot[0] + wtot[1] + wtot[2] + wtot[3];
    const unsigned int chitot = wchi[0] + wchi[1] + wchi[2] + wchi[3];
    unsigned int pos = wbase + inc - cwin;     // exclusive prefix across block

    // ---- write candidates at private offsets (no atomics) ----
#pragma unroll
    for (int j = 0; j < ELEMS_PER_THREAD; ++j) {
        unsigned int key = keys[j];
        if (key >= WIN_LO_KEY && key < WIN_HI_KEY) {
            if (pos < (unsigned int)LCAP) lbuf[pos] = key;
            ++pos;
        }
    }
    __syncthreads();

    if (t == 0) { bcnt[bid] = total; bchi[bid] = chitot; }
    const unsigned int wcnt = (total < (unsigned int)LCAP) ? total : (unsigned int)LCAP;
    unsigned int* mycand = cand + (size_t)bid * LCAP;
    for (unsigned int i = t; i < wcnt; i += NTHREADS) mycand[i] = lbuf[i];
}

// ============================================================================
// Per-sample select: stage candidates into dense LDS (wave-per-segment --
// R8 post-mortem: the serial 64-burst staging loop was ~15-20 us of exposed
// load latency), then 2-level radix (10+10 bits of key-WIN_LO) in LDS.
// Fallback (window miss / overflow): exact 3-level radix scanning h.
// ============================================================================
__global__ __launch_bounds__(NTH2) void select_cand(const unsigned int* __restrict__ cand,
                                                    const unsigned int* __restrict__ bcnt,
                                                    const unsigned int* __restrict__ bchi,
                                                    const float* __restrict__ h,
                                                    unsigned int* __restrict__ cutk,
                                                    unsigned int need_total,
                                                    unsigned int rank) {
    __shared__ unsigned int dense[DCAP];     // 64 KB
    __shared__ unsigned int lh[NBA];         // 4 KB
    __shared__ unsigned int part[NTH2];      // 4 KB
    __shared__ unsigned int cnts[64], excl[64], chired[64];
    __shared__ unsigned int sb1, sr1, sb2, sr2, sb3, sr3;
    __shared__ unsigned int s_ovf, s_cn;
    const int n = blockIdx.x;
    const int t = threadIdx.x;

    if (t == 0) s_ovf = 0u;
    if (t < 64) { cnts[t] = bcnt[(n << 6) + t]; chired[t] = bchi[(n << 6) + t]; }
    __syncthreads();
    if (t < 64 && cnts[t] > (unsigned int)LCAP) atomicOr(&s_ovf, 1u);
    if (t < 64) part[t] = cnts[t];
    __syncthreads();
    for (int off = 1; off < 64; off <<= 1) {
        unsigned int v = (t >= off && t < 64) ? part[t - off] : 0u;
        __syncthreads();
        if (t < 64) part[t] += v;
        __syncthreads();
    }
    if (t < 64) excl[t] = part[t] - cnts[t];
    if (t == 63) s_cn = part[63];
    __syncthreads();
    for (int off = 32; off > 0; off >>= 1) {
        if (t < off) chired[t] += chired[t + off];
        __syncthreads();
    }
    const unsigned int cn  = s_cn;
    const unsigned int chi = chired[0];
    const bool in_win = (s_ovf == 0u) && (cn <= (unsigned int)DCAP) &&
                        (chi < need_total) && (chi + cn >= need_total);

    if (in_win) {
        // ---- stage segments into dense LDS: wave-per-segment (16-way parallel) ----
        const int wv = t >> 6, ln = t & 63;
        for (int j = 0; j < 4; ++j) {
            const int c = wv + (j << 4);             // 16 waves cover 64 segments
            const unsigned int bc  = cnts[c];
            const unsigned int off = excl[c];
            const unsigned int* src = cand + (size_t)((n << 6) + c) * LCAP;
            for (unsigned int i = ln; i < bc; i += 64) dense[off + i] = src[i];
        }
        __syncthreads();
        const unsigned int rp = cn - (need_total - chi);   // ascending rank in cands

        // ---- level A: (key - WIN_LO) >> 10, 1024 bins ----
        for (int i = t; i < NBA; i += NTH2) lh[i] = 0;
        __syncthreads();
        for (unsigned int i = t; i < cn; i += NTH2)
            atomicAdd(&lh[(dense[i] - WIN_LO_KEY) >> 10], 1u);
        __syncthreads();
        find_binT<NTH2>(lh, NBA, rp, part, &sb1, &sr1);
        const unsigned int cb = sb1, r2 = sr1;

        // ---- level B: low 10 bits within coarse bin cb ----
        for (int i = t; i < NB10; i += NTH2) lh[i] = 0;
        __syncthreads();
        for (unsigned int i = t; i < cn; i += NTH2) {
            unsigned int wv2 = dense[i] - WIN_LO_KEY;
            if ((wv2 >> 10) == cb) atomicAdd(&lh[wv2 & 0x3FFu], 1u);
        }
        __syncthreads();
        find_binT<NTH2>(lh, NB10, r2, part, &sb2, &sr2);
        if (t == 0) cutk[n] = WIN_LO_KEY + (cb << 10) + sb2;
        return;
    }

    // ---------- exact fallback: 3-level radix over full sample ----------
    const float* hp = h + (size_t)n * CHW;
    unsigned int* lhF = dense;               // DCAP >= 4096

    for (int i = t; i < NB12; i += NTH2) lhF[i] = 0;
    __syncthreads();
    for (unsigned int i = t; i < (unsigned int)CHW; i += NTH2)
        atomicAdd(&lhF[akey(hp[i]) >> 19], 1u);
    __syncthreads();
    find_binT<NTH2>(lhF, NB12, rank, part, &sb1, &sr1);
    const unsigned int b1 = sb1, r1 = sr1;

    for (int i = t; i < NB12; i += NTH2) lhF[i] = 0;
    __syncthreads();
    for (unsigned int i = t; i < (unsigned int)CHW; i += NTH2) {
        unsigned int key = akey(hp[i]);
        if ((key >> 19) == b1) atomicAdd(&lhF[(key >> 7) & 0xFFFu], 1u);
    }
    __syncthreads();
    find_binT<NTH2>(lhF, NB12, r1, part, &sb2, &sr2);
    const unsigned int b2 = sb2, r2f = sr2;
    const unsigned int p24 = (b1 << 12) | b2;

    for (int i = t; i < NB7; i += NTH2) lhF[i] = 0;
    __syncthreads();
    for (unsigned int i = t; i < (unsigned int)CHW; i += NTH2) {
        unsigned int key = akey(hp[i]);
        if ((key >> 7) == p24) atomicAdd(&lhF[key & 0x7Fu], 1u);
    }
    __syncthreads();
    find_binT<NTH2>(lhF, NB7, r2f, part, &sb3, &sr3);
    if (t == 0) cutk[n] = (p24 << 7) | sb3;
}

// ---------------- Apply: out = h * (key >= cutoff ? 1.0 : (1 - tau)) ----------------
// Non-temporal stores: keep h resident in L3 for re-reads.
__global__ __launch_bounds__(NTHREADS) void apply_kernel(const f32x4* __restrict__ h,
                                                         const float* __restrict__ tau,
                                                         const unsigned int* __restrict__ cutoff,
                                                         f32x4* __restrict__ out) {
    const int n = blockIdx.x >> 6;
    const int chunk = blockIdx.x & 63;
    const unsigned int c = cutoff[n];
    const float t = tau[0];
    const float lo = 1.0f - t;
    const size_t base = (size_t)n * F4_PER_SAMPLE + (size_t)chunk * F4_PER_BLOCK;
    const int tid = threadIdx.x;
#pragma unroll
    for (int k = 0; k < F4_PER_THREAD; ++k) {
        f32x4 v = h[base + k * NTHREADS + tid];
        f32x4 o;
        o.x = v.x * ((akey(v.x) >= c) ? 1.0f : lo);
        o.y = v.y * ((akey(v.y) >= c) ? 1.0f : lo);
        o.z = v.z * ((akey(v.z) >= c) ? 1.0f : lo);
        o.w = v.w * ((akey(v.w) >= c) ? 1.0f : lo);
        __builtin_nontemporal_store(o, &out[base + k * NTHREADS + tid]);
    }
}

// ============================================================================
// FALLBACK PIPELINE (small d_ws): 3-pass radix select (R2 structure)
// ============================================================================
__global__ __launch_bounds__(NTHREADS) void hist_pass1(const float4* __restrict__ h,
                                                       unsigned int* __restrict__ hist) {
    __shared__ unsigned int lh[NB12];
    const int t = threadIdx.x;
    for (int i = t; i < NB12; i += NTHREADS) lh[i] = 0;
    __syncthreads();
    const float4* p = h + (size_t)blockIdx.x * F4_PER_BLOCK;
    const int n = blockIdx.x >> 6;
#pragma unroll
    for (int k = 0; k < F4_PER_THREAD; ++k) {
        float4 v = p[k * NTHREADS + t];
        atomicAdd(&lh[akey(v.x) >> 19], 1u);
        atomicAdd(&lh[akey(v.y) >> 19], 1u);
        atomicAdd(&lh[akey(v.z) >> 19], 1u);
        atomicAdd(&lh[akey(v.w) >> 19], 1u);
    }
    __syncthreads();
    unsigned int* gh = hist + (size_t)n * NB12;
    for (int i = t; i < NB12; i += NTHREADS) {
        unsigned int v = lh[i];
        if (v) atomicAdd(&gh[i], v);
    }
}

__global__ __launch_bounds__(NTHREADS) void hist_pass2(const float4* __restrict__ h,
                                                       const unsigned int* __restrict__ state_bits,
                                                       unsigned int* __restrict__ hist) {
    __shared__ unsigned int lh[NB12];
    const int t = threadIdx.x;
    for (int i = t; i < NB12; i += NTHREADS) lh[i] = 0;
    __syncthreads();
    const int n = blockIdx.x >> 6;
    const unsigned int b1 = state_bits[n];
    const float4* p = h + (size_t)blockIdx.x * F4_PER_BLOCK;
#pragma unroll
    for (int k = 0; k < F4_PER_THREAD; ++k) {
        float4 v = p[k * NTHREADS + t];
        unsigned int ka = akey(v.x), kb = akey(v.y), kc = akey(v.z), kd = akey(v.w);
        if ((ka >> 19) == b1) atomicAdd(&lh[(ka >> 7) & 0xFFFu], 1u);
        if ((kb >> 19) == b1) atomicAdd(&lh[(kb >> 7) & 0xFFFu], 1u);
        if ((kc >> 19) == b1) atomicAdd(&lh[(kc >> 7) & 0xFFFu], 1u);
        if ((kd >> 19) == b1) atomicAdd(&lh[(kd >> 7) & 0xFFFu], 1u);
    }
    __syncthreads();
    unsigned int* gh = hist + (size_t)n * NB12;
    for (int i = t; i < NB12; i += NTHREADS) {
        unsigned int v = lh[i];
        if (v) atomicAdd(&gh[i], v);
    }
}

__global__ __launch_bounds__(NTHREADS) void hist_pass3(const float4* __restrict__ h,
                                                       const unsigned int* __restrict__ state_bits,
                                                       unsigned int* __restrict__ hist) {
    __shared__ unsigned int lh[NB7];
    const int t = threadIdx.x;
    for (int i = t; i < NB7; i += NTHREADS) lh[i] = 0;
    __syncthreads();
    const int n = blockIdx.x >> 6;
    const unsigned int p24 = state_bits[n];
    const float4* p = h + (size_t)blockIdx.x * F4_PER_BLOCK;
#pragma unroll
    for (int k = 0; k < F4_PER_THREAD; ++k) {
        float4 v = p[k * NTHREADS + t];
        unsigned int ka = akey(v.x), kb = akey(v.y), kc = akey(v.z), kd = akey(v.w);
        if ((ka >> 7) == p24) atomicAdd(&lh[ka & 0x7Fu], 1u);
        if ((kb >> 7) == p24) atomicAdd(&lh[kb & 0x7Fu], 1u);
        if ((kc >> 7) == p24) atomicAdd(&lh[kc & 0x7Fu], 1u);
        if ((kd >> 7) == p24) atomicAdd(&lh[kd & 0x7Fu], 1u);
    }
    __syncthreads();
    unsigned int* gh = hist + (size_t)n * NB7;
    for (int i = t; i < NB7; i += NTHREADS) {
        unsigned int v = lh[i];
        if (v) atomicAdd(&gh[i], v);
    }
}

__global__ __launch_bounds__(NTHREADS) void select_pass(const unsigned int* __restrict__ hist,
                                                        int nbins, int pass,
                                                        unsigned int* __restrict__ state_bits,
                                                        unsigned int* __restrict__ state_rank,
                                                        unsigned int* __restrict__ cutoff,
                                                        unsigned int init_rank) {
    __shared__ unsigned int part[NTHREADS];
    __shared__ unsigned int sbin, srem;
    const int n = blockIdx.x;
    const int t = threadIdx.x;
    const unsigned int* gh = hist + (size_t)n * nbins;
    const unsigned int r = (pass == 0) ? init_rank : state_rank[n];
    find_binT<NTHREADS>(gh, nbins, r, part, &sbin, &srem);
    if (t == 0) {
        if (pass == 0) { state_bits[n] = sbin; state_rank[n] = srem; }
        else if (pass == 1) { state_bits[n] = (state_bits[n] << 12) | sbin; state_rank[n] = srem; }
        else { cutoff[n] = (state_bits[n] << 7) | sbin; }
    }
}

extern "C" void kernel_launch(void* const* d_in, const int* in_sizes, int n_in,
                              void* d_out, int out_size, void* d_ws, size_t ws_size,
                              hipStream_t stream) {
    const float* h = (const float*)d_in[0];
    const float* tau = (const float*)d_in[1];
    float* out = (float*)d_out;

    const int total = in_sizes[0];
    const int N = total / CHW;              // 64
    const int NBLK = N * BLOCKS_PER_SAMPLE; // 4096

    const int k0 = (int)(0.1 * (double)CHW);                       // 52428
    const unsigned int init_rank = (unsigned int)(CHW - 1 - k0);   // 471859
    const unsigned int need_total = (unsigned int)CHW - init_rank; // 52429

    dim3 grid((unsigned)NBLK), blk(NTHREADS);

    // ---- fast path layout: bcnt[NBLK] | bchi[NBLK] | cutk[N] | cand[NBLK*LCAP] ----
    const size_t fast_words = 2 * (size_t)NBLK + (size_t)N + (size_t)NBLK * LCAP;
    if (ws_size >= fast_words * 4) {
        unsigned int* bcnt = (unsigned int*)d_ws;
        unsigned int* bchi = bcnt + NBLK;
        unsigned int* cutk = bchi + NBLK;
        unsigned int* cand = cutk + N;

        win_compact<<<grid, blk, 0, stream>>>((const float4*)h, cand, bcnt, bchi);
        select_cand<<<N, NTH2, 0, stream>>>(cand, bcnt, bchi, h, cutk,
                                            need_total, init_rank);
        apply_kernel<<<grid, blk, 0, stream>>>((const f32x4*)h, tau, cutk, (f32x4*)out);
        return;
    }

    // ---- fallback pipeline: original 3-pass path (needs ~2.2 MB ws) ----
    unsigned int* hist1 = (unsigned int*)d_ws;
    unsigned int* hist2 = hist1 + (size_t)N * NB12;
    unsigned int* hist3 = hist2 + (size_t)N * NB12;
    unsigned int* sbits = hist3 + (size_t)N * NB7;
    unsigned int* srank = sbits + N;
    unsigned int* cutk  = srank + N;
    const int zwords = 2 * N * NB12 + N * NB7 + 3 * N;

    zero_ws<<<(zwords + NTHREADS - 1) / NTHREADS, blk, 0, stream>>>(hist1, zwords);
    hist_pass1<<<grid, blk, 0, stream>>>((const float4*)h, hist1);
    select_pass<<<N, blk, 0, stream>>>(hist1, NB12, 0, sbits, srank, cutk, init_rank);
    hist_pass2<<<grid, blk, 0, stream>>>((const float4*)h, sbits, hist2);
    select_pass<<<N, blk, 0, stream>>>(hist2, NB12, 1, sbits, srank, cutk, 0u);
    hist_pass3<<<grid, blk, 0, stream>>>((const float4*)h, sbits, hist3);
    select_pass<<<N, blk, 0, stream>>>(hist3, NB7, 2, sbits, srank, cutk, 0u);
    apply_kernel<<<grid, blk, 0, stream>>>((const f32x4*)h, tau, cutk, (f32x4*)out);
}

// Round 10
// 75.318 us; speedup vs baseline: 42.6313x; 1.0730x over previous
//
#include <hip/hip_runtime.h>
#include <cstdint>
#include <cstddef>

// Problem geometry (fixed by reference setup_inputs):
//   h: (64, 512, 32, 32) fp32;  chw = 512*32*32 = 2^19
//   k0 = int(0.1 * chw) = 52428; ascending rank = chw-1-k0 = 471859
//   need = chw - rank = 52429 elements are >= cutoff
//   out = h * (|h| >= cutoff ? 1.0 : (1 - tau))
#define CHW 524288
#define F4_PER_SAMPLE (CHW / 4)            // 131072
#define BLOCKS_PER_SAMPLE 64
#define F4_PER_BLOCK (F4_PER_SAMPLE / BLOCKS_PER_SAMPLE)  // 2048 float4 = 32 KiB
#define NTHREADS 256
#define F4_PER_THREAD (F4_PER_BLOCK / NTHREADS)           // 8
#define ELEMS_PER_THREAD (F4_PER_THREAD * 4)              // 32
#define NB12 4096
#define NB10 1024
#define NB7  128
#define LCAP 512         // per-block candidate cap (mean ~131, sd ~11.4 -> 33 sigma)
#define NTH2 1024        // select_cand block size (16 waves)
#define DCAP 16384       // dense LDS candidate cap (mean ~8.4k, sd ~90)
#define NBA  640         // level-A bins: window span (0xA0000)>>10
// Candidate window [1.609375, 1.6875). cutoff ~ 1.645 +- 0.004 ->
// margins 8.9 sigma (low) / 10.6 sigma (high); chi-side 21 / 18 sigma.
#define WIN_LO_KEY 0x3FCE0000u   // bits(1.609375f)
#define WIN_HI_KEY 0x3FD80000u   // bits(1.6875f)

typedef float f32x4 __attribute__((ext_vector_type(4)));

__device__ __forceinline__ unsigned int akey(float x) {
    return __float_as_uint(x) & 0x7FFFFFFFu;   // monotonic key for |x|
}

// ---------------- zero workspace words (fallback pipeline only) ----------------
__global__ __launch_bounds__(NTHREADS) void zero_ws(unsigned int* __restrict__ p, int words) {
    int i = blockIdx.x * NTHREADS + threadIdx.x;
    if (i < words) p[i] = 0u;
}

// ---------------- wave-level inclusive scan (64 lanes, shfl) ----------------
__device__ __forceinline__ unsigned int wave_iscan(unsigned int v, int lane) {
#pragma unroll
    for (int off = 1; off < 64; off <<= 1) {
        unsigned int u = __shfl_up(v, off);
        if (lane >= off) v += u;
    }
    return v;
}

// ---------------- find bin containing rank r: shfl-scan version (R9 post-
// mortem: Hillis-Steele over part[NT] was ~20 barriers per call; this is 2).
template<int NT>
__device__ __forceinline__ void find_bin2(const unsigned int* lh, int nbins,
                                          unsigned int r,
                                          unsigned int* sbin, unsigned int* srem) {
    __shared__ unsigned int wsum[NT / 64];
    const int t = threadIdx.x, ln = t & 63, wv = t >> 6;
    const int bpt = (nbins + NT - 1) / NT;
    unsigned int s = 0;
    const int b0 = t * bpt;
#pragma unroll 4
    for (int i = 0; i < bpt; ++i) { int b = b0 + i; if (b < nbins) s += lh[b]; }
    unsigned int inc = wave_iscan(s, ln);
    if (ln == 63) wsum[wv] = inc;
    __syncthreads();
    if (wv == 0 && ln < NT / 64) {
        unsigned int x = wsum[ln];
#pragma unroll
        for (int off = 1; off < NT / 64; off <<= 1) {
            unsigned int u = __shfl_up(x, off, NT / 64);
            if (ln >= off) x += u;
        }
        wsum[ln] = x;
    }
    __syncthreads();
    const unsigned int base = (wv > 0) ? wsum[wv - 1] : 0u;
    const unsigned int excl = base + inc - s;
    if (s > 0 && r >= excl && r < excl + s) {
        unsigned int acc = excl;
        for (int i = 0; i < bpt; ++i) {
            int b = b0 + i;
            unsigned int c = (b < nbins) ? lh[b] : 0u;
            if (r < acc + c) { *sbin = (unsigned int)b; *srem = r - acc; break; }
            acc += c;
        }
    }
    __syncthreads();
}

// ============================================================================
// Pass 1: register-staged count + compact into PER-BLOCK private segments.
// ============================================================================
__global__ __launch_bounds__(NTHREADS) void win_compact(const float4* __restrict__ h,
                                                        unsigned int* __restrict__ cand,
                                                        unsigned int* __restrict__ bcnt,
                                                        unsigned int* __restrict__ bchi) {
    __shared__ unsigned int lbuf[LCAP];
    __shared__ unsigned int wtot[4], wchi[4];
    const int t = threadIdx.x;
    const int lane = t & 63;
    const int w = t >> 6;
    const int bid = blockIdx.x;
    const float4* p = h + (size_t)bid * F4_PER_BLOCK;

    float4 vv[F4_PER_THREAD];
#pragma unroll
    for (int k = 0; k < F4_PER_THREAD; ++k) vv[k] = p[k * NTHREADS + t];
    unsigned int keys[ELEMS_PER_THREAD];
#pragma unroll
    for (int k = 0; k < F4_PER_THREAD; ++k) {
        keys[4 * k + 0] = akey(vv[k].x);
        keys[4 * k + 1] = akey(vv[k].y);
        keys[4 * k + 2] = akey(vv[k].z);
        keys[4 * k + 3] = akey(vv[k].w);
    }

    unsigned int chi = 0, cwin = 0;
#pragma unroll
    for (int j = 0; j < ELEMS_PER_THREAD; ++j) {
        chi  += (keys[j] >= WIN_HI_KEY) ? 1u : 0u;
        cwin += (keys[j] >= WIN_LO_KEY && keys[j] < WIN_HI_KEY) ? 1u : 0u;
    }

    unsigned int inc = wave_iscan(cwin, lane);
    unsigned int wc = chi;
#pragma unroll
    for (int off = 32; off > 0; off >>= 1) wc += __shfl_xor(wc, off);

    if (lane == 63) wtot[w] = inc;
    if (lane == 0)  wchi[w] = wc;
    __syncthreads();

    unsigned int wbase = 0;
#pragma unroll
    for (int i = 0; i < 4; ++i) if (i < w) wbase += wtot[i];
    const unsigned int total  = wtot[0] + wtot[1] + wtot[2] + wtot[3];
    const unsigned int chitot = wchi[0] + wchi[1] + wchi[2] + wchi[3];
    unsigned int pos = wbase + inc - cwin;     // exclusive prefix across block

#pragma unroll
    for (int j = 0; j < ELEMS_PER_THREAD; ++j) {
        unsigned int key = keys[j];
        if (key >= WIN_LO_KEY && key < WIN_HI_KEY) {
            if (pos < (unsigned int)LCAP) lbuf[pos] = key;
            ++pos;
        }
    }
    __syncthreads();

    if (t == 0) { bcnt[bid] = total; bchi[bid] = chitot; }
    const unsigned int wcnt = (total < (unsigned int)LCAP) ? total : (unsigned int)LCAP;
    unsigned int* mycand = cand + (size_t)bid * LCAP;
    for (unsigned int i = t; i < wcnt; i += NTHREADS) mycand[i] = lbuf[i];
}

// ============================================================================
// Per-sample select: wave-0 bookkeeping + wave-per-segment staging +
// 2-level radix in LDS, all scans shfl-based (~8 barriers total).
// Fallback (window miss / overflow): exact 3-level radix scanning h.
// ============================================================================
__global__ __launch_bounds__(NTH2) void select_cand(const unsigned int* __restrict__ cand,
                                                    const unsigned int* __restrict__ bcnt,
                                                    const unsigned int* __restrict__ bchi,
                                                    const float* __restrict__ h,
                                                    unsigned int* __restrict__ cutk,
                                                    unsigned int need_total,
                                                    unsigned int rank) {
    __shared__ unsigned int dense[DCAP];     // 64 KB
    __shared__ unsigned int lh[NB10];        // 4 KB (covers NBA=640 too)
    __shared__ unsigned int cnts[64], excl[64];
    __shared__ unsigned int sb1, sr1, sb2, sr2, sb3, sr3;
    __shared__ unsigned int s_ovf, s_cn, s_chi;
    const int n = blockIdx.x;
    const int t = threadIdx.x;

    // ---- wave-0 bookkeeping: load counts, scan, reduce chi, ovf ballot ----
    if (t < 64) {
        unsigned int c  = bcnt[(n << 6) + t];
        unsigned int ch = bchi[(n << 6) + t];
        cnts[t] = c;
        unsigned long long m = __ballot(c > (unsigned int)LCAP);
        unsigned int inc = wave_iscan(c, t);
        excl[t] = inc - c;
        unsigned int chs = ch;
#pragma unroll
        for (int off = 32; off > 0; off >>= 1) chs += __shfl_xor(chs, off);
        if (t == 63) s_cn = inc;
        if (t == 0) { s_chi = chs; s_ovf = (m != 0ull) ? 1u : 0u; }
    }
    __syncthreads();
    const unsigned int cn  = s_cn;
    const unsigned int chi = s_chi;
    const bool in_win = (s_ovf == 0u) && (cn <= (unsigned int)DCAP) &&
                        (chi < need_total) && (chi + cn >= need_total);

    if (in_win) {
        // ---- stage segments into dense LDS: wave-per-segment (16-way) ----
        const int wv = t >> 6, ln = t & 63;
        for (int j = 0; j < 4; ++j) {
            const int c = wv + (j << 4);
            const unsigned int bc  = cnts[c];
            const unsigned int off = excl[c];
            const unsigned int* src = cand + (size_t)((n << 6) + c) * LCAP;
            for (unsigned int i = ln; i < bc; i += 64) dense[off + i] = src[i];
        }
        // zero level-A hist before barrier (independent)
        for (int i = t; i < NBA; i += NTH2) lh[i] = 0;
        __syncthreads();
        const unsigned int rp = cn - (need_total - chi);   // ascending rank in cands

        // ---- level A: (key - WIN_LO) >> 10, 640 bins ----
        for (unsigned int i = t; i < cn; i += NTH2)
            atomicAdd(&lh[(dense[i] - WIN_LO_KEY) >> 10], 1u);
        __syncthreads();
        find_bin2<NTH2>(lh, NBA, rp, &sb1, &sr1);
        const unsigned int cb = sb1, r2 = sr1;

        // ---- level B: low 10 bits within coarse bin cb ----
        for (int i = t; i < NB10; i += NTH2) lh[i] = 0;
        __syncthreads();
        for (unsigned int i = t; i < cn; i += NTH2) {
            unsigned int wv2 = dense[i] - WIN_LO_KEY;
            if ((wv2 >> 10) == cb) atomicAdd(&lh[wv2 & 0x3FFu], 1u);
        }
        __syncthreads();
        find_bin2<NTH2>(lh, NB10, r2, &sb2, &sr2);
        if (t == 0) cutk[n] = WIN_LO_KEY + (cb << 10) + sb2;
        return;
    }

    // ---------- exact fallback: 3-level radix over full sample ----------
    const float* hp = h + (size_t)n * CHW;
    unsigned int* lhF = dense;               // DCAP >= 4096

    for (int i = t; i < NB12; i += NTH2) lhF[i] = 0;
    __syncthreads();
    for (unsigned int i = t; i < (unsigned int)CHW; i += NTH2)
        atomicAdd(&lhF[akey(hp[i]) >> 19], 1u);
    __syncthreads();
    find_bin2<NTH2>(lhF, NB12, rank, &sb1, &sr1);
    const unsigned int b1 = sb1, r1 = sr1;

    for (int i = t; i < NB12; i += NTH2) lhF[i] = 0;
    __syncthreads();
    for (unsigned int i = t; i < (unsigned int)CHW; i += NTH2) {
        unsigned int key = akey(hp[i]);
        if ((key >> 19) == b1) atomicAdd(&lhF[(key >> 7) & 0xFFFu], 1u);
    }
    __syncthreads();
    find_bin2<NTH2>(lhF, NB12, r1, &sb2, &sr2);
    const unsigned int b2 = sb2, r2f = sr2;
    const unsigned int p24 = (b1 << 12) | b2;

    for (int i = t; i < NB7; i += NTH2) lhF[i] = 0;
    __syncthreads();
    for (unsigned int i = t; i < (unsigned int)CHW; i += NTH2) {
        unsigned int key = akey(hp[i]);
        if ((key >> 7) == p24) atomicAdd(&lhF[key & 0x7Fu], 1u);
    }
    __syncthreads();
    find_bin2<NTH2>(lhF, NB7, r2f, &sb3, &sr3);
    if (t == 0) cutk[n] = (p24 << 7) | sb3;
}

// ---------------- Apply: out = h * (key >= cutoff ? 1.0 : (1 - tau)) ----------------
// Non-temporal stores: keep h resident in L3 for re-reads.
__global__ __launch_bounds__(NTHREADS) void apply_kernel(const f32x4* __restrict__ h,
                                                         const float* __restrict__ tau,
                                                         const unsigned int* __restrict__ cutoff,
                                                         f32x4* __restrict__ out) {
    const int n = blockIdx.x >> 6;
    const int chunk = blockIdx.x & 63;
    const unsigned int c = cutoff[n];
    const float t = tau[0];
    const float lo = 1.0f - t;
    const size_t base = (size_t)n * F4_PER_SAMPLE + (size_t)chunk * F4_PER_BLOCK;
    const int tid = threadIdx.x;
#pragma unroll
    for (int k = 0; k < F4_PER_THREAD; ++k) {
        f32x4 v = h[base + k * NTHREADS + tid];
        f32x4 o;
        o.x = v.x * ((akey(v.x) >= c) ? 1.0f : lo);
        o.y = v.y * ((akey(v.y) >= c) ? 1.0f : lo);
        o.z = v.z * ((akey(v.z) >= c) ? 1.0f : lo);
        o.w = v.w * ((akey(v.w) >= c) ? 1.0f : lo);
        __builtin_nontemporal_store(o, &out[base + k * NTHREADS + tid]);
    }
}

// ============================================================================
// FALLBACK PIPELINE (small d_ws): 3-pass radix select (R2 structure)
// ============================================================================
__global__ __launch_bounds__(NTHREADS) void hist_pass1(const float4* __restrict__ h,
                                                       unsigned int* __restrict__ hist) {
    __shared__ unsigned int lh[NB12];
    const int t = threadIdx.x;
    for (int i = t; i < NB12; i += NTHREADS) lh[i] = 0;
    __syncthreads();
    const float4* p = h + (size_t)blockIdx.x * F4_PER_BLOCK;
    const int n = blockIdx.x >> 6;
#pragma unroll
    for (int k = 0; k < F4_PER_THREAD; ++k) {
        float4 v = p[k * NTHREADS + t];
        atomicAdd(&lh[akey(v.x) >> 19], 1u);
        atomicAdd(&lh[akey(v.y) >> 19], 1u);
        atomicAdd(&lh[akey(v.z) >> 19], 1u);
        atomicAdd(&lh[akey(v.w) >> 19], 1u);
    }
    __syncthreads();
    unsigned int* gh = hist + (size_t)n * NB12;
    for (int i = t; i < NB12; i += NTHREADS) {
        unsigned int v = lh[i];
        if (v) atomicAdd(&gh[i], v);
    }
}

__global__ __launch_bounds__(NTHREADS) void hist_pass2(const float4* __restrict__ h,
                                                       const unsigned int* __restrict__ state_bits,
                                                       unsigned int* __restrict__ hist) {
    __shared__ unsigned int lh[NB12];
    const int t = threadIdx.x;
    for (int i = t; i < NB12; i += NTHREADS) lh[i] = 0;
    __syncthreads();
    const int n = blockIdx.x >> 6;
    const unsigned int b1 = state_bits[n];
    const float4* p = h + (size_t)blockIdx.x * F4_PER_BLOCK;
#pragma unroll
    for (int k = 0; k < F4_PER_THREAD; ++k) {
        float4 v = p[k * NTHREADS + t];
        unsigned int ka = akey(v.x), kb = akey(v.y), kc = akey(v.z), kd = akey(v.w);
        if ((ka >> 19) == b1) atomicAdd(&lh[(ka >> 7) & 0xFFFu], 1u);
        if ((kb >> 19) == b1) atomicAdd(&lh[(kb >> 7) & 0xFFFu], 1u);
        if ((kc >> 19) == b1) atomicAdd(&lh[(kc >> 7) & 0xFFFu], 1u);
        if ((kd >> 19) == b1) atomicAdd(&lh[(kd >> 7) & 0xFFFu], 1u);
    }
    __syncthreads();
    unsigned int* gh = hist + (size_t)n * NB12;
    for (int i = t; i < NB12; i += NTHREADS) {
        unsigned int v = lh[i];
        if (v) atomicAdd(&gh[i], v);
    }
}

__global__ __launch_bounds__(NTHREADS) void hist_pass3(const float4* __restrict__ h,
                                                       const unsigned int* __restrict__ state_bits,
                                                       unsigned int* __restrict__ hist) {
    __shared__ unsigned int lh[NB7];
    const int t = threadIdx.x;
    for (int i = t; i < NB7; i += NTHREADS) lh[i] = 0;
    __syncthreads();
    const int n = blockIdx.x >> 6;
    const unsigned int p24 = state_bits[n];
    const float4* p = h + (size_t)blockIdx.x * F4_PER_BLOCK;
#pragma unroll
    for (int k = 0; k < F4_PER_THREAD; ++k) {
        float4 v = p[k * NTHREADS + t];
        unsigned int ka = akey(v.x), kb = akey(v.y), kc = akey(v.z), kd = akey(v.w);
        if ((ka >> 7) == p24) atomicAdd(&lh[ka & 0x7Fu], 1u);
        if ((kb >> 7) == p24) atomicAdd(&lh[kb & 0x7Fu], 1u);
        if ((kc >> 7) == p24) atomicAdd(&lh[kc & 0x7Fu], 1u);
        if ((kd >> 7) == p24) atomicAdd(&lh[kd & 0x7Fu], 1u);
    }
    __syncthreads();
    unsigned int* gh = hist + (size_t)n * NB7;
    for (int i = t; i < NB7; i += NTHREADS) {
        unsigned int v = lh[i];
        if (v) atomicAdd(&gh[i], v);
    }
}

__global__ __launch_bounds__(NTH2) void select_pass(const unsigned int* __restrict__ hist,
                                                    int nbins, int pass,
                                                    unsigned int* __restrict__ state_bits,
                                                    unsigned int* __restrict__ state_rank,
                                                    unsigned int* __restrict__ cutoff,
                                                    unsigned int init_rank) {
    __shared__ unsigned int sbin, srem;
    const int n = blockIdx.x;
    const int t = threadIdx.x;
    const unsigned int* gh = hist + (size_t)n * nbins;
    const unsigned int r = (pass == 0) ? init_rank : state_rank[n];
    find_bin2<NTH2>(gh, nbins, r, &sbin, &srem);
    if (t == 0) {
        if (pass == 0) { state_bits[n] = sbin; state_rank[n] = srem; }
        else if (pass == 1) { state_bits[n] = (state_bits[n] << 12) | sbin; state_rank[n] = srem; }
        else { cutoff[n] = (state_bits[n] << 7) | sbin; }
    }
}

extern "C" void kernel_launch(void* const* d_in, const int* in_sizes, int n_in,
                              void* d_out, int out_size, void* d_ws, size_t ws_size,
                              hipStream_t stream) {
    const float* h = (const float*)d_in[0];
    const float* tau = (const float*)d_in[1];
    float* out = (float*)d_out;

    const int total = in_sizes[0];
    const int N = total / CHW;              // 64
    const int NBLK = N * BLOCKS_PER_SAMPLE; // 4096

    const int k0 = (int)(0.1 * (double)CHW);                       // 52428
    const unsigned int init_rank = (unsigned int)(CHW - 1 - k0);   // 471859
    const unsigned int need_total = (unsigned int)CHW - init_rank; // 52429

    dim3 grid((unsigned)NBLK), blk(NTHREADS);

    // ---- fast path layout: bcnt[NBLK] | bchi[NBLK] | cutk[N] | cand[NBLK*LCAP] ----
    const size_t fast_words = 2 * (size_t)NBLK + (size_t)N + (size_t)NBLK * LCAP;
    if (ws_size >= fast_words * 4) {
        unsigned int* bcnt = (unsigned int*)d_ws;
        unsigned int* bchi = bcnt + NBLK;
        unsigned int* cutk = bchi + NBLK;
        unsigned int* cand = cutk + N;

        win_compact<<<grid, blk, 0, stream>>>((const float4*)h, cand, bcnt, bchi);
        select_cand<<<N, NTH2, 0, stream>>>(cand, bcnt, bchi, h, cutk,
                                            need_total, init_rank);
        apply_kernel<<<grid, blk, 0, stream>>>((const f32x4*)h, tau, cutk, (f32x4*)out);
        return;
    }

    // ---- fallback pipeline: original 3-pass path (needs ~2.2 MB ws) ----
    unsigned int* hist1 = (unsigned int*)d_ws;
    unsigned int* hist2 = hist1 + (size_t)N * NB12;
    unsigned int* hist3 = hist2 + (size_t)N * NB12;
    unsigned int* sbits = hist3 + (size_t)N * NB7;
    unsigned int* srank = sbits + N;
    unsigned int* cutk  = srank + N;
    const int zwords = 2 * N * NB12 + N * NB7 + 3 * N;

    zero_ws<<<(zwords + NTHREADS - 1) / NTHREADS, blk, 0, stream>>>(hist1, zwords);
    hist_pass1<<<grid, blk, 0, stream>>>((const float4*)h, hist1);
    select_pass<<<N, NTH2, 0, stream>>>(hist1, NB12, 0, sbits, srank, cutk, init_rank);
    hist_pass2<<<grid, blk, 0, stream>>>((const float4*)h, sbits, hist2);
    select_pass<<<N, NTH2, 0, stream>>>(hist2, NB12, 1, sbits, srank, cutk, 0u);
    hist_pass3<<<grid, blk, 0, stream>>>((const float4*)h, sbits, hist3);
    select_pass<<<N, NTH2, 0, stream>>>(hist3, NB7, 2, sbits, srank, cutk, 0u);
    apply_kernel<<<grid, blk, 0, stream>>>((const f32x4*)h, tau, cutk, (f32x4*)out);
}